// Round 16
// baseline (281.631 us; speedup 1.0000x reference)
//
#include <hip/hip_runtime.h>
#include <hip/hip_bf16.h>

typedef __attribute__((ext_vector_type(8))) short short8;
typedef __attribute__((ext_vector_type(4))) float floatx4;

#if __has_builtin(__builtin_amdgcn_exp2f)
#define EXP2(x) __builtin_amdgcn_exp2f(x)
#else
#define EXP2(x) exp2f(x)
#endif

#define BAR() __builtin_amdgcn_s_barrier()
#define FENCE() asm volatile("" ::: "memory")
#define WAIT_LGKM0() asm volatile("s_waitcnt lgkmcnt(0)" ::: "memory")
#define WAIT_VM(n) asm volatile("s_waitcnt vmcnt(" #n ")" ::: "memory")

__device__ __forceinline__ short f2bf(float f) {
  __hip_bfloat16 h = __float2bfloat16(f);
  return *reinterpret_cast<const short*>(&h);
}

__device__ __forceinline__ short8 cvt_f32x8_bf16(const float* __restrict__ p) {
  float4 a = *reinterpret_cast<const float4*>(p);
  float4 b = *reinterpret_cast<const float4*>(p + 4);
  short8 r;
  r[0] = f2bf(a.x); r[1] = f2bf(a.y); r[2] = f2bf(a.z); r[3] = f2bf(a.w);
  r[4] = f2bf(b.x); r[5] = f2bf(b.y); r[6] = f2bf(b.z); r[7] = f2bf(b.w);
  return r;
}

typedef const __attribute__((address_space(1))) void* gptr1;
typedef __attribute__((address_space(3))) void* lptr3;
__device__ __forceinline__ void gl_lds16(const void* g, void* l) {
  __builtin_amdgcn_global_load_lds((gptr1)g, (lptr3)l, 16, 0, 0);
}

// fused 3-weight conversion
__global__ __launch_bounds__(256)
void conv_weights(const float* __restrict__ Wkv, const float* __restrict__ Wq,
                  const float* __restrict__ Wproj, short* __restrict__ wkvb,
                  short* __restrict__ wqb, short* __restrict__ wprojb) {
  const float* src; short* dst; int off;
  int i = blockIdx.x * 256 + threadIdx.x;
  if (blockIdx.x < 1024)      { src = Wkv;   dst = wkvb;   off = i; }
  else if (blockIdx.x < 1536) { src = Wq;    dst = wqb;    off = i - 1024 * 256; }
  else                        { src = Wproj; dst = wprojb; off = i - 1536 * 256; }
  short8 v = cvt_f32x8_bf16(src + (size_t)off * 8);
  *reinterpret_cast<short8*>(dst + (size_t)off * 8) = v;
}

// ============ 256x256 8-phase GEMM for kv: C = A[M,K]*B[N,K]^T ===========
// A is FP32 (x read directly — no conversion kernel). A staged via reg:
// loads issued ph1/ph2, cvt+ds_write ph3/ph4 (T14 split on the 8-phase ring).
// The cvt's compiler vmcnt is in-order -> also retires older B gl_lds, so
// no manual vmcnt needed. B via gl_lds (bf16 weights), wrap-staged mod NT.
// col<1024 -> k_ws bf16 [M][1024] ; col>=1024 -> vt[b,h,d=64][n=4096]
__global__ __launch_bounds__(512, 2)
void gemm256_kv(const float* __restrict__ A, const short* __restrict__ B,
                short* __restrict__ k_out, short* __restrict__ vt,
                int M, int N, int K)
{
  __shared__ __align__(16) short lds[2][2][2][128 * 64]; // [parity][A/B][slot][row*64]

  const int tid  = threadIdx.x;
  const int lane = tid & 63;
  const int w    = tid >> 6;
  const int wm   = w >> 2;
  const int wn   = w & 3;
  const int cl   = lane & 15;
  const int hi   = lane >> 4;
  const int srl  = lane >> 3;
  const int gch8 = (((lane & 7) ^ srl) << 3);

  const int ntile = N >> 8;
  int bid = blockIdx.x;
  { int cpx = gridDim.x >> 3; bid = (bid & 7) * cpx + (bid >> 3); }
  const int tm = bid / ntile, tn = bid % ntile;
  const int m0 = tm << 8, n0 = tn << 8;
  const int NT = K >> 6;

  struct Aregs { float4 v[4]; };
  auto loadA = [&](Aregs& r, int slot, int ktX) {
    #pragma unroll
    for (int j = 0; j < 2; ++j) {
      const int sr = (w << 4) + (j << 3) + srl;
      const int tr = ((sr >> 6) << 7) + (slot << 6) + (sr & 63);
      const float* p = A + (size_t)(m0 + tr) * K + ktX + gch8;
      r.v[j * 2]     = *reinterpret_cast<const float4*>(p);
      r.v[j * 2 + 1] = *reinterpret_cast<const float4*>(p + 4);
    }
  };
  auto writeA = [&](const Aregs& r, int par, int slot) {
    #pragma unroll
    for (int j = 0; j < 2; ++j) {
      const float4& a  = r.v[j * 2];
      const float4& b2 = r.v[j * 2 + 1];
      short8 o;
      o[0] = f2bf(a.x);  o[1] = f2bf(a.y);  o[2] = f2bf(a.z);  o[3] = f2bf(a.w);
      o[4] = f2bf(b2.x); o[5] = f2bf(b2.y); o[6] = f2bf(b2.z); o[7] = f2bf(b2.w);
      *reinterpret_cast<short8*>(
          &lds[par][0][slot][((w << 4) + (j << 3)) * 64 + lane * 8]) = o;
    }
  };
  auto stageB = [&](int par, int slot, int ktX) {
    #pragma unroll
    for (int j = 0; j < 2; ++j) {
      const int sr = (w << 4) + (j << 3) + srl;
      const int tr = ((sr >> 5) << 6) + (slot << 5) + (sr & 31);
      gl_lds16(B + (size_t)(n0 + tr) * K + ktX + gch8,
               (void*)&lds[par][1][slot][((w << 4) + (j << 3)) * 64]);
    }
  };

  const floatx4 fzero = {0.f, 0.f, 0.f, 0.f};
  floatx4 acc[8][4];
  #pragma unroll
  for (int m = 0; m < 8; ++m)
    #pragma unroll
    for (int n = 0; n < 4; ++n)
      acc[m][n] = fzero;

  short8 af[4][2], b0[2][2], b1[2][2];

  auto readA = [&](int par, int slot) {
    #pragma unroll
    for (int m = 0; m < 4; ++m)
      #pragma unroll
      for (int ks = 0; ks < 2; ++ks) {
        const int sr = (wm << 6) + (m << 4) + cl;
        const int cpos = ((((ks << 2) + hi) ^ (sr & 7)) << 3);
        af[m][ks] = *reinterpret_cast<const short8*>(&lds[par][0][slot][sr * 64 + cpos]);
      }
  };
  auto readB = [&](int par, int slot, short8 (&bf)[2][2]) {
    #pragma unroll
    for (int n = 0; n < 2; ++n)
      #pragma unroll
      for (int ks = 0; ks < 2; ++ks) {
        const int sr = (wn << 5) + (n << 4) + cl;
        const int cpos = ((((ks << 2) + hi) ^ (sr & 7)) << 3);
        bf[n][ks] = *reinterpret_cast<const short8*>(&lds[par][1][slot][sr * 64 + cpos]);
      }
  };

  #define QUAD(BF, MH, NH)                                                     \
    __builtin_amdgcn_s_setprio(1);                                             \
    _Pragma("unroll")                                                          \
    for (int ks = 0; ks < 2; ++ks)                                             \
      _Pragma("unroll")                                                        \
      for (int m = 0; m < 4; ++m)                                              \
        _Pragma("unroll")                                                      \
        for (int n = 0; n < 2; ++n)                                            \
          acc[(MH)*4 + m][(NH)*2 + n] = __builtin_amdgcn_mfma_f32_16x16x32_bf16( \
              af[m][ks], BF[n][ks], acc[(MH)*4 + m][(NH)*2 + n], 0, 0, 0);     \
    __builtin_amdgcn_s_setprio(0);

  // ---- prologue: A0[0],A1[0],A0[1] reg-staged; B0/B1 of tiles 0,1 via gl_lds
  {
    Aregs pa00, pa10, pa01;
    loadA(pa00, 0, 0); loadA(pa10, 1, 0); loadA(pa01, 0, 64);
    stageB(0, 0, 0); stageB(0, 1, 0); stageB(1, 0, 64); stageB(1, 1, 64);
    writeA(pa00, 0, 0); writeA(pa10, 0, 1); writeA(pa01, 1, 0);
    WAIT_VM(0); BAR(); FENCE();
  }

  Aregs ra1, ra0;
  for (int t = 0; t < NT; ++t) {
    const int p  = t & 1;
    const int pn = p ^ 1;
    const int t1 = t + 1;
    const int t2 = t + 2;
    int t2w = t2; if (t2w >= NT) t2w -= NT;   // B wrap (harmless re-stage)

    // phase 1: read A0,B0 ; issue A1[t+1] fp32 loads
    readA(p, 0); readB(p, 0, b0);
    if (t1 < NT) loadA(ra1, 1, t1 << 6);
    BAR(); WAIT_LGKM0();
    QUAD(b0, 0, 0);
    BAR(); FENCE();

    // phase 2: read B1 ; issue A0[t+2] fp32 loads
    readB(p, 1, b1);
    if (t2 < NT) loadA(ra0, 0, t2 << 6);
    BAR(); WAIT_LGKM0();
    QUAD(b1, 0, 1);
    BAR(); FENCE();

    // phase 3: read A1 ; write A1[t+1] (auto-vmcnt retires older B gl_lds too)
    readA(p, 1);
    if (t1 < NT) writeA(ra1, pn, 1);
    stageB(p, 0, t2w << 6);
    BAR(); WAIT_LGKM0();
    QUAD(b0, 1, 0);
    BAR(); FENCE();

    // phase 4: write A0[t+2] ; issue B1[t+2]
    if (t2 < NT) writeA(ra0, p, 0);
    stageB(p, 1, t2w << 6);
    BAR(); WAIT_LGKM0();
    QUAD(b1, 1, 1);
    BAR(); FENCE();
  }
  WAIT_VM(0);

  const int rq = hi << 2;
  #pragma unroll
  for (int Mi = 0; Mi < 8; ++Mi) {
    #pragma unroll
    for (int Nn = 0; Nn < 4; ++Nn) {
      const int grow = m0 + wm * 128 + Mi * 16 + rq;
      const int gcol = n0 + wn * 64 + Nn * 16 + cl;
      if (gcol < 1024) {
        #pragma unroll
        for (int i = 0; i < 4; ++i)
          k_out[(size_t)(grow + i) * 1024 + gcol] = f2bf(acc[Mi][Nn][i]);
      } else {
        const int d  = gcol - 1024;
        const int bb = grow >> 12;
        const int nn = grow & 4095;
        size_t base = ((size_t)(bb * 16 + (d >> 6)) * 64 + (d & 63)) * 4096 + nn;
        short4 pk;
        pk.x = f2bf(acc[Mi][Nn][0]); pk.y = f2bf(acc[Mi][Nn][1]);
        pk.z = f2bf(acc[Mi][Nn][2]); pk.w = f2bf(acc[Mi][Nn][3]);
        *reinterpret_cast<short4*>(&vt[base]) = pk;
      }
    }
  }
}

// ---------------- 64x64-tile GEMM for skinny projections ------------------
// 4 blocks/CU. AFP32: A fp32 reg-staged with inline cvt (no conv kernel).
// MODE 0: bf16*oscale; MODE 2: f32 + bias.
template<int MODE, bool AFP32>
__global__ __launch_bounds__(256, 4)
void gemm64(const void* __restrict__ Ap, const short* __restrict__ B,
            void* __restrict__ O0, const float* __restrict__ bias,
            int M, int N, int K, float oscale)
{
  __shared__ __align__(16) short As[64 * 64];
  __shared__ __align__(16) short Bs[64 * 64];

  const int tid  = threadIdx.x;
  const int lane = tid & 63;
  const int w    = tid >> 6;
  const int ntile = N >> 6;
  int bid = blockIdx.x;
  { int cpx = gridDim.x >> 3; bid = (bid & 7) * cpx + (bid >> 3); }
  const int tm = bid / ntile;
  const int tn = bid % ntile;
  const int m0 = tm << 6, n0 = tn << 6;
  const int wr = (w >> 1) << 5;
  const int wc = (w & 1) << 5;
  const int cl = lane & 15;
  const int hi = lane >> 4;
  const int srow = lane >> 3;
  const int scol = (lane & 7) << 3;

  const floatx4 fzero = {0.f, 0.f, 0.f, 0.f};
  floatx4 acc[2][2];
  #pragma unroll
  for (int m = 0; m < 2; ++m)
    #pragma unroll
    for (int n = 0; n < 2; ++n)
      acc[m][n] = fzero;

  for (int kt = 0; kt < K; kt += 64) {
    if (AFP32) {
      const float* Af = (const float*)Ap;
      #pragma unroll
      for (int sgm = 0; sgm < 2; ++sgm) {
        const int seg = tid + sgm * 256;       // 0..511
        const int row = seg >> 3;
        const int c8  = (seg & 7) << 3;
        short8 v = cvt_f32x8_bf16(Af + (size_t)(m0 + row) * K + kt + c8);
        *reinterpret_cast<short8*>(&As[row * 64 + c8]) = v;
      }
    } else {
      const short* Ab = (const short*)Ap;
      #pragma unroll
      for (int i = 0; i < 2; ++i) {
        const int chunk = (w << 1) + i;
        const int row   = (chunk << 3) + srow;
        gl_lds16(Ab + (size_t)(m0 + row) * K + kt + scol, &As[chunk * 512]);
      }
    }
    #pragma unroll
    for (int i = 0; i < 2; ++i) {
      const int chunk = (w << 1) + i;
      const int row   = (chunk << 3) + srow;
      gl_lds16(B + (size_t)(n0 + row) * K + kt + scol, &Bs[chunk * 512]);
    }
    __syncthreads();

    #pragma unroll
    for (int ks = 0; ks < 2; ++ks) {
      short8 af[2], bfr[2];
      #pragma unroll
      for (int m = 0; m < 2; ++m)
        af[m] = *reinterpret_cast<const short8*>(
            &As[(wr + m * 16 + cl) * 64 + ks * 32 + (hi << 3)]);
      #pragma unroll
      for (int n = 0; n < 2; ++n)
        bfr[n] = *reinterpret_cast<const short8*>(
            &Bs[(wc + n * 16 + cl) * 64 + ks * 32 + (hi << 3)]);
      #pragma unroll
      for (int m = 0; m < 2; ++m)
        #pragma unroll
        for (int n = 0; n < 2; ++n)
          acc[m][n] = __builtin_amdgcn_mfma_f32_16x16x32_bf16(af[m], bfr[n], acc[m][n], 0, 0, 0);
    }
    __syncthreads();
  }

  const int rq = hi << 2;
  #pragma unroll
  for (int m = 0; m < 2; ++m) {
    #pragma unroll
    for (int n = 0; n < 2; ++n) {
      const int grow = m0 + wr + m * 16 + rq;
      const int gcol = n0 + wc + n * 16 + cl;
      if (MODE == 0) {
        short* o = (short*)O0;
        #pragma unroll
        for (int i = 0; i < 4; ++i)
          o[(size_t)(grow + i) * N + gcol] = f2bf(acc[m][n][i] * oscale);
      } else {
        float* o = (float*)O0;
        const float bv = bias[gcol];
        #pragma unroll
        for (int i = 0; i < 4; ++i)
          o[(size_t)(grow + i) * N + gcol] = acc[m][n][i] + bv;
      }
    }
  }
}

// ---------------- flash attention (round-15, measured 80.3 µs) -----------
__global__ __launch_bounds__(256, 3)
void attn_fwd(const short* __restrict__ q_ws, const short* __restrict__ k_ws,
              const short* __restrict__ vt_ws, short* __restrict__ ao_ws)
{
  __shared__ __align__(16) short Ks[2][64 * 64];
  __shared__ __align__(16) short Vts[2][64 * 64];
  __shared__ __align__(16) short Pl[4][32 * 64];

  const int tid  = threadIdx.x;
  const int lane = tid & 63;
  const int w    = tid >> 6;
  const int i    = blockIdx.x;
  const int bh   = (i & 7) * 8 + (i >> 6);
  const int qt   = (i >> 3) & 7;
  const int b  = bh >> 4;
  const int h  = bh & 15;
  const int q0 = qt * 128 + w * 32;
  const int cl = lane & 15;
  const int hi = lane >> 4;
  const int rq = hi << 2;
  const int key7 = cl & 7;

  short8 qf[2][2];
  #pragma unroll
  for (int tt = 0; tt < 2; ++tt)
    #pragma unroll
    for (int ks = 0; ks < 2; ++ks) {
      size_t idx = (size_t)(b * 1024 + q0 + tt * 16 + cl) * 1024
                 + h * 64 + ks * 32 + (hi << 3);
      qf[tt][ks] = *reinterpret_cast<const short8*>(&q_ws[idx]);
    }

  int koff[2];
  #pragma unroll
  for (int ks = 0; ks < 2; ++ks)
    koff[ks] = cl * 64 + ((((ks << 2) + hi) ^ key7) << 3);
  const int pwc   = hi >> 1;
  const int pwoff = (hi & 1) << 2;
  int pwch[4];
  #pragma unroll
  for (int n = 0; n < 4; ++n)
    pwch[n] = ((((n << 1) + pwc) ^ key7) << 3) + pwoff + cl * 64;

  const floatx4 fzero = {0.f, 0.f, 0.f, 0.f};
  floatx4 o[2][4];
  floatx4 ol[2];
  floatx4 s[4][2];
  short8 vones;
  #pragma unroll
  for (int j = 0; j < 8; ++j) vones[j] = (short)0x3F80;
  #pragma unroll
  for (int tt = 0; tt < 2; ++tt) {
    ol[tt] = fzero;
    #pragma unroll
    for (int nd = 0; nd < 4; ++nd) o[tt][nd] = fzero;
  }

  const int c0    = w << 1;
  const int srow8 = lane >> 3;
  const int gch8  = (((lane & 7) ^ srow8) << 3);
  const short* kbase = k_ws + (size_t)(b * 4096 + (c0 << 3) + srow8) * 1024 + h * 64 + gch8;
  const short* vbase = vt_ws + ((size_t)bh * 64 + (c0 << 3) + srow8) * 4096 + gch8;

  auto stage = [&](int buf, int kv0) {
    gl_lds16(kbase + (size_t)kv0 * 1024,          (void*)&Ks[buf][c0 * 512]);
    gl_lds16(kbase + (size_t)kv0 * 1024 + 8192,   (void*)&Ks[buf][(c0 + 1) * 512]);
    gl_lds16(vbase + kv0,                          (void*)&Vts[buf][c0 * 512]);
    gl_lds16(vbase + kv0 + 8 * 4096,               (void*)&Vts[buf][(c0 + 1) * 512]);
  };

  auto qk = [&](const short* kb) {
    short8 kf[2][4];
    #pragma unroll
    for (int ks = 0; ks < 2; ++ks)
      #pragma unroll
      for (int n = 0; n < 4; ++n)
        kf[ks][n] = *reinterpret_cast<const short8*>(kb + koff[ks] + n * 1024);
    #pragma unroll
    for (int n = 0; n < 4; ++n)
      #pragma unroll
      for (int tt = 0; tt < 2; ++tt)
        s[n][tt] = __builtin_amdgcn_mfma_f32_16x16x32_bf16(
            kf[1][n], qf[tt][1],
            __builtin_amdgcn_mfma_f32_16x16x32_bf16(kf[0][n], qf[tt][0], fzero, 0, 0, 0),
            0, 0, 0);
  };
  auto pv = [&](const short* plb, const short* vb) {
    #pragma unroll
    for (int ks = 0; ks < 2; ++ks) {
      short8 pa[2], vf[4];
      #pragma unroll
      for (int tt = 0; tt < 2; ++tt)
        pa[tt] = *reinterpret_cast<const short8*>(plb + koff[ks] + tt * 1024);
      #pragma unroll
      for (int nd = 0; nd < 4; ++nd)
        vf[nd] = *reinterpret_cast<const short8*>(vb + koff[ks] + nd * 1024);
      #pragma unroll
      for (int tt = 0; tt < 2; ++tt) {
        ol[tt] = __builtin_amdgcn_mfma_f32_16x16x32_bf16(pa[tt], vones, ol[tt], 0, 0, 0);
        #pragma unroll
        for (int nd = 0; nd < 4; ++nd)
          o[tt][nd] = __builtin_amdgcn_mfma_f32_16x16x32_bf16(pa[tt], vf[nd], o[tt][nd], 0, 0, 0);
      }
    }
  };
  auto smax = [&](short* plw) {
    #pragma unroll
    for (int tt = 0; tt < 2; ++tt)
      #pragma unroll
      for (int n = 0; n < 4; ++n) {
        short4 pk;
        #pragma unroll
        for (int ii = 0; ii < 4; ++ii)
          pk[ii] = f2bf(EXP2(s[n][tt][ii]));
        *reinterpret_cast<short4*>(plw + tt * 1024 + pwch[n]) = pk;
      }
  };

  stage(0, 0);
  WAIT_VM(0); BAR(); FENCE();
  qk(&Ks[0][0]);
  stage(1, 64);
  smax(&Pl[w][0]);

  for (int t = 0; t < 63; ++t) {
    const int cur = t & 1;
    WAIT_VM(0); BAR(); FENCE();
    __builtin_amdgcn_s_setprio(1);
    qk(&Ks[cur ^ 1][0]);
    pv(&Pl[w][0], &Vts[cur][0]);
    __builtin_amdgcn_s_setprio(0);
    FENCE(); BAR();
    stage(cur, ((t + 2) & 63) << 6);
    WAIT_LGKM0();
    smax(&Pl[w][0]);
  }
  __builtin_amdgcn_s_setprio(1);
  pv(&Pl[w][0], &Vts[1][0]);
  __builtin_amdgcn_s_setprio(0);
  WAIT_VM(0);

  #pragma unroll
  for (int m = 0; m < 2; ++m) {
    float inv[4];
    #pragma unroll
    for (int ii = 0; ii < 4; ++ii)
      inv[ii] = 1.f / ol[m][ii];
    #pragma unroll
    for (int nd = 0; nd < 4; ++nd)
      #pragma unroll
      for (int ii = 0; ii < 4; ++ii) {
        size_t idx = (size_t)(b * 1024 + q0 + m * 16 + rq + ii) * 1024
                   + h * 64 + nd * 16 + cl;
        ao_ws[idx] = f2bf(o[m][nd][ii] * inv[ii]);
      }
  }
}

extern "C" void kernel_launch(void* const* d_in, const int* in_sizes, int n_in,
                              void* d_out, int out_size, void* d_ws, size_t ws_size,
                              hipStream_t stream)
{
  const float* x     = (const float*)d_in[0];
  const float* query = (const float*)d_in[1];
  const float* Wq    = (const float*)d_in[2];
  const float* Wkv   = (const float*)d_in[3];
  const float* Wproj = (const float*)d_in[4];
  const float* bproj = (const float*)d_in[5];
  float* out = (float*)d_out;

  const float QSCALE = 0.18033688011112042f;  // (1/sqrt(64)) * log2(e)

  char* ws = (char*)d_ws;
  short* k_ws   = (short*)(ws);
  short* vt_ws  = (short*)(ws + (32ull << 20));
  short* q_ws   = (short*)(ws + (64ull << 20));
  short* ao_ws  = (short*)(ws + (72ull << 20));
  short* wkvb   = (short*)(ws + (96ull << 20));
  short* wqb    = (short*)(ws + (100ull << 20));
  short* wprojb = (short*)(ws + (102ull << 20));

  conv_weights<<<dim3(2048), 256, 0, stream>>>(Wkv, Wq, Wproj, wkvb, wqb, wprojb);
  // kv = x @ Wkv^T  (x fp32 read directly, reg-staged)
  gemm256_kv<<<dim3(512), 512, 0, stream>>>(x, wkvb, k_ws, vt_ws,
                                            16384, 2048, 1024);
  // q = (query @ Wq^T) * QSCALE  (query fp32 read directly)
  gemm64<0, true><<<dim3(1024), 256, 0, stream>>>(query, wqb, q_ws, nullptr,
                                                  4096, 1024, 1024, QSCALE);
  attn_fwd<<<dim3(512), 256, 0, stream>>>(q_ws, k_ws, vt_ws, ao_ws);
  gemm64<2, false><<<dim3(1024), 256, 0, stream>>>(ao_ws, wprojb, out, bproj,
                                                   4096, 1024, 1024, 1.0f);
}

// Round 17
// 215.002 us; speedup vs baseline: 1.3099x; 1.3099x over previous
//
#include <hip/hip_runtime.h>
#include <hip/hip_bf16.h>

typedef __attribute__((ext_vector_type(8))) short short8;
typedef __attribute__((ext_vector_type(4))) float floatx4;

#if __has_builtin(__builtin_amdgcn_exp2f)
#define EXP2(x) __builtin_amdgcn_exp2f(x)
#else
#define EXP2(x) exp2f(x)
#endif

#define BAR() __builtin_amdgcn_s_barrier()
#define FENCE() asm volatile("" ::: "memory")
#define WAIT_LGKM0() asm volatile("s_waitcnt lgkmcnt(0)" ::: "memory")
#define WAIT_VM(n) asm volatile("s_waitcnt vmcnt(" #n ")" ::: "memory")

__device__ __forceinline__ short f2bf(float f) {
  __hip_bfloat16 h = __float2bfloat16(f);
  return *reinterpret_cast<const short*>(&h);
}

__device__ __forceinline__ short8 cvt_f32x8_bf16(const float* __restrict__ p) {
  float4 a = *reinterpret_cast<const float4*>(p);
  float4 b = *reinterpret_cast<const float4*>(p + 4);
  short8 r;
  r[0] = f2bf(a.x); r[1] = f2bf(a.y); r[2] = f2bf(a.z); r[3] = f2bf(a.w);
  r[4] = f2bf(b.x); r[5] = f2bf(b.y); r[6] = f2bf(b.z); r[7] = f2bf(b.w);
  return r;
}

typedef const __attribute__((address_space(1))) void* gptr1;
typedef __attribute__((address_space(3))) void* lptr3;
__device__ __forceinline__ void gl_lds16(const void* g, void* l) {
  __builtin_amdgcn_global_load_lds((gptr1)g, (lptr3)l, 16, 0, 0);
}

// ---------------- fp32 -> bf16 conversion (memory-bound) ----------------
__global__ __launch_bounds__(256)
void f32_to_bf16(const float* __restrict__ in, short* __restrict__ out, int n8) {
  int i = blockIdx.x * blockDim.x + threadIdx.x;
  if (i < n8) {
    short8 v = cvt_f32x8_bf16(in + (size_t)i * 8);
    *reinterpret_cast<short8*>(out + (size_t)i * 8) = v;
  }
}

// fused 3-weight conversion
__global__ __launch_bounds__(256)
void conv_weights(const float* __restrict__ Wkv, const float* __restrict__ Wq,
                  const float* __restrict__ Wproj, short* __restrict__ wkvb,
                  short* __restrict__ wqb, short* __restrict__ wprojb) {
  const float* src; short* dst; int off;
  int i = blockIdx.x * 256 + threadIdx.x;
  if (blockIdx.x < 1024)      { src = Wkv;   dst = wkvb;   off = i; }
  else if (blockIdx.x < 1536) { src = Wq;    dst = wqb;    off = i - 1024 * 256; }
  else                        { src = Wproj; dst = wprojb; off = i - 1536 * 256; }
  short8 v = cvt_f32x8_bf16(src + (size_t)off * 8);
  *reinterpret_cast<short8*>(dst + (size_t)off * 8) = v;
}

// ============ 256x256 8-phase GEMM for kv: C = A[M,K]*B[N,K]^T ===========
// (round-13/15 version, measured ~81 µs) A,B bf16 via global_load_lds.
// col<1024 -> k_ws bf16 [M][1024] ; col>=1024 -> vt[b,h,d=64][n=4096]
__global__ __launch_bounds__(512, 2)
void gemm256_kv(const short* __restrict__ A, const short* __restrict__ B,
                short* __restrict__ k_out, short* __restrict__ vt,
                int M, int N, int K)
{
  __shared__ __align__(16) short lds[2][2][2][128 * 64]; // [parity][A/B][slot][row*64]

  const int tid  = threadIdx.x;
  const int lane = tid & 63;
  const int w    = tid >> 6;
  const int wm   = w >> 2;
  const int wn   = w & 3;
  const int cl   = lane & 15;
  const int hi   = lane >> 4;
  const int srl  = lane >> 3;
  const int gch8 = (((lane & 7) ^ srl) << 3);

  const int ntile = N >> 8;
  int bid = blockIdx.x;
  { int cpx = gridDim.x >> 3; bid = (bid & 7) * cpx + (bid >> 3); }
  const int tm = bid / ntile, tn = bid % ntile;
  const int m0 = tm << 8, n0 = tn << 8;
  const int NT = K >> 6;

  auto stageA = [&](int par, int slot, int ktX) {
    #pragma unroll
    for (int j = 0; j < 2; ++j) {
      const int sr = (w << 4) + (j << 3) + srl;
      const int tr = ((sr >> 6) << 7) + (slot << 6) + (sr & 63);
      gl_lds16(A + (size_t)(m0 + tr) * K + ktX + gch8,
               (void*)&lds[par][0][slot][((w << 4) + (j << 3)) * 64]);
    }
  };
  auto stageB = [&](int par, int slot, int ktX) {
    #pragma unroll
    for (int j = 0; j < 2; ++j) {
      const int sr = (w << 4) + (j << 3) + srl;
      const int tr = ((sr >> 5) << 6) + (slot << 5) + (sr & 31);
      gl_lds16(B + (size_t)(n0 + tr) * K + ktX + gch8,
               (void*)&lds[par][1][slot][((w << 4) + (j << 3)) * 64]);
    }
  };

  const floatx4 fzero = {0.f, 0.f, 0.f, 0.f};
  floatx4 acc[8][4];
  #pragma unroll
  for (int m = 0; m < 8; ++m)
    #pragma unroll
    for (int n = 0; n < 4; ++n)
      acc[m][n] = fzero;

  short8 af[4][2], b0[2][2], b1[2][2];

  auto readA = [&](int par, int slot) {
    #pragma unroll
    for (int m = 0; m < 4; ++m)
      #pragma unroll
      for (int ks = 0; ks < 2; ++ks) {
        const int sr = (wm << 6) + (m << 4) + cl;
        const int cpos = ((((ks << 2) + hi) ^ (sr & 7)) << 3);
        af[m][ks] = *reinterpret_cast<const short8*>(&lds[par][0][slot][sr * 64 + cpos]);
      }
  };
  auto readB = [&](int par, int slot, short8 (&bf)[2][2]) {
    #pragma unroll
    for (int n = 0; n < 2; ++n)
      #pragma unroll
      for (int ks = 0; ks < 2; ++ks) {
        const int sr = (wn << 5) + (n << 4) + cl;
        const int cpos = ((((ks << 2) + hi) ^ (sr & 7)) << 3);
        bf[n][ks] = *reinterpret_cast<const short8*>(&lds[par][1][slot][sr * 64 + cpos]);
      }
  };

  #define QUAD(BF, MH, NH)                                                     \
    __builtin_amdgcn_s_setprio(1);                                             \
    _Pragma("unroll")                                                          \
    for (int ks = 0; ks < 2; ++ks)                                             \
      _Pragma("unroll")                                                        \
      for (int m = 0; m < 4; ++m)                                              \
        _Pragma("unroll")                                                      \
        for (int n = 0; n < 2; ++n)                                            \
          acc[(MH)*4 + m][(NH)*2 + n] = __builtin_amdgcn_mfma_f32_16x16x32_bf16( \
              af[m][ks], BF[n][ks], acc[(MH)*4 + m][(NH)*2 + n], 0, 0, 0);     \
    __builtin_amdgcn_s_setprio(0);

  stageA(0, 0, 0); stageB(0, 0, 0); stageB(0, 1, 0); stageA(0, 1, 0);
  stageA(1, 0, 64); stageB(1, 0, 64); stageB(1, 1, 64);
  WAIT_VM(6); BAR(); FENCE();

  for (int t = 0; t < NT; ++t) {
    const int p  = t & 1;
    const int pn = p ^ 1;
    int t1 = t + 1; if (t1 >= NT) t1 -= NT;
    int t2 = t + 2; if (t2 >= NT) t2 -= NT;
    const int kt1 = t1 << 6;
    const int kt2 = t2 << 6;

    readA(p, 0); readB(p, 0, b0);
    stageA(pn, 1, kt1);
    BAR(); WAIT_LGKM0();
    QUAD(b0, 0, 0);
    BAR(); FENCE();

    readB(p, 1, b1);
    stageA(p, 0, kt2);
    BAR(); WAIT_LGKM0();
    QUAD(b1, 0, 1);
    BAR(); FENCE();

    readA(p, 1);
    stageB(p, 0, kt2);
    BAR(); WAIT_LGKM0();
    QUAD(b0, 1, 0);
    BAR(); FENCE();

    stageB(p, 1, kt2);
    WAIT_VM(6);
    BAR(); WAIT_LGKM0();
    QUAD(b1, 1, 1);
    BAR(); FENCE();
  }
  WAIT_VM(0);

  const int rq = hi << 2;
  #pragma unroll
  for (int Mi = 0; Mi < 8; ++Mi) {
    #pragma unroll
    for (int Nn = 0; Nn < 4; ++Nn) {
      const int grow = m0 + wm * 128 + Mi * 16 + rq;
      const int gcol = n0 + wn * 64 + Nn * 16 + cl;
      if (gcol < 1024) {
        #pragma unroll
        for (int i = 0; i < 4; ++i)
          k_out[(size_t)(grow + i) * 1024 + gcol] = f2bf(acc[Mi][Nn][i]);
      } else {
        const int d  = gcol - 1024;
        const int bb = grow >> 12;
        const int nn = grow & 4095;
        size_t base = ((size_t)(bb * 16 + (d >> 6)) * 64 + (d & 63)) * 4096 + nn;
        short4 pk;
        pk.x = f2bf(acc[Mi][Nn][0]); pk.y = f2bf(acc[Mi][Nn][1]);
        pk.z = f2bf(acc[Mi][Nn][2]); pk.w = f2bf(acc[Mi][Nn][3]);
        *reinterpret_cast<short4*>(&vt[base]) = pk;
      }
    }
  }
}

// ---------------- 64x64-tile GEMM for skinny projections ------------------
// 4 blocks/CU. AFP32: A fp32 reg-staged with inline cvt (OK here: cross-block
// TLP at 4 blocks/CU hides the staging latency, unlike the 1-block kv ring).
// MODE 0: bf16*oscale; MODE 2: f32 + bias.
template<int MODE, bool AFP32>
__global__ __launch_bounds__(256, 4)
void gemm64(const void* __restrict__ Ap, const short* __restrict__ B,
            void* __restrict__ O0, const float* __restrict__ bias,
            int M, int N, int K, float oscale)
{
  __shared__ __align__(16) short As[64 * 64];
  __shared__ __align__(16) short Bs[64 * 64];

  const int tid  = threadIdx.x;
  const int lane = tid & 63;
  const int w    = tid >> 6;
  const int ntile = N >> 6;
  int bid = blockIdx.x;
  { int cpx = gridDim.x >> 3; bid = (bid & 7) * cpx + (bid >> 3); }
  const int tm = bid / ntile;
  const int tn = bid % ntile;
  const int m0 = tm << 6, n0 = tn << 6;
  const int wr = (w >> 1) << 5;
  const int wc = (w & 1) << 5;
  const int cl = lane & 15;
  const int hi = lane >> 4;
  const int srow = lane >> 3;
  const int scol = (lane & 7) << 3;

  const floatx4 fzero = {0.f, 0.f, 0.f, 0.f};
  floatx4 acc[2][2];
  #pragma unroll
  for (int m = 0; m < 2; ++m)
    #pragma unroll
    for (int n = 0; n < 2; ++n)
      acc[m][n] = fzero;

  for (int kt = 0; kt < K; kt += 64) {
    if (AFP32) {
      const float* Af = (const float*)Ap;
      #pragma unroll
      for (int sgm = 0; sgm < 2; ++sgm) {
        const int seg = tid + sgm * 256;       // 0..511
        const int row = seg >> 3;
        const int c8  = (seg & 7) << 3;
        short8 v = cvt_f32x8_bf16(Af + (size_t)(m0 + row) * K + kt + c8);
        *reinterpret_cast<short8*>(&As[row * 64 + c8]) = v;
      }
    } else {
      const short* Ab = (const short*)Ap;
      #pragma unroll
      for (int i = 0; i < 2; ++i) {
        const int chunk = (w << 1) + i;
        const int row   = (chunk << 3) + srow;
        gl_lds16(Ab + (size_t)(m0 + row) * K + kt + scol, &As[chunk * 512]);
      }
    }
    #pragma unroll
    for (int i = 0; i < 2; ++i) {
      const int chunk = (w << 1) + i;
      const int row   = (chunk << 3) + srow;
      gl_lds16(B + (size_t)(n0 + row) * K + kt + scol, &Bs[chunk * 512]);
    }
    __syncthreads();

    #pragma unroll
    for (int ks = 0; ks < 2; ++ks) {
      short8 af[2], bfr[2];
      #pragma unroll
      for (int m = 0; m < 2; ++m)
        af[m] = *reinterpret_cast<const short8*>(
            &As[(wr + m * 16 + cl) * 64 + ks * 32 + (hi << 3)]);
      #pragma unroll
      for (int n = 0; n < 2; ++n)
        bfr[n] = *reinterpret_cast<const short8*>(
            &Bs[(wc + n * 16 + cl) * 64 + ks * 32 + (hi << 3)]);
      #pragma unroll
      for (int m = 0; m < 2; ++m)
        #pragma unroll
        for (int n = 0; n < 2; ++n)
          acc[m][n] = __builtin_amdgcn_mfma_f32_16x16x32_bf16(af[m], bfr[n], acc[m][n], 0, 0, 0);
    }
    __syncthreads();
  }

  const int rq = hi << 2;
  #pragma unroll
  for (int m = 0; m < 2; ++m) {
    #pragma unroll
    for (int n = 0; n < 2; ++n) {
      const int grow = m0 + wr + m * 16 + rq;
      const int gcol = n0 + wc + n * 16 + cl;
      if (MODE == 0) {
        short* o = (short*)O0;
        #pragma unroll
        for (int i = 0; i < 4; ++i)
          o[(size_t)(grow + i) * N + gcol] = f2bf(acc[m][n][i] * oscale);
      } else {
        float* o = (float*)O0;
        const float bv = bias[gcol];
        #pragma unroll
        for (int i = 0; i < 4; ++i)
          o[(size_t)(grow + i) * N + gcol] = acc[m][n][i] + bv;
      }
    }
  }
}

// ---------------- flash attention (round-15, measured 80.3 µs) -----------
__global__ __launch_bounds__(256, 3)
void attn_fwd(const short* __restrict__ q_ws, const short* __restrict__ k_ws,
              const short* __restrict__ vt_ws, short* __restrict__ ao_ws)
{
  __shared__ __align__(16) short Ks[2][64 * 64];
  __shared__ __align__(16) short Vts[2][64 * 64];
  __shared__ __align__(16) short Pl[4][32 * 64];

  const int tid  = threadIdx.x;
  const int lane = tid & 63;
  const int w    = tid >> 6;
  const int i    = blockIdx.x;
  const int bh   = (i & 7) * 8 + (i >> 6);
  const int qt   = (i >> 3) & 7;
  const int b  = bh >> 4;
  const int h  = bh & 15;
  const int q0 = qt * 128 + w * 32;
  const int cl = lane & 15;
  const int hi = lane >> 4;
  const int rq = hi << 2;
  const int key7 = cl & 7;

  short8 qf[2][2];
  #pragma unroll
  for (int tt = 0; tt < 2; ++tt)
    #pragma unroll
    for (int ks = 0; ks < 2; ++ks) {
      size_t idx = (size_t)(b * 1024 + q0 + tt * 16 + cl) * 1024
                 + h * 64 + ks * 32 + (hi << 3);
      qf[tt][ks] = *reinterpret_cast<const short8*>(&q_ws[idx]);
    }

  int koff[2];
  #pragma unroll
  for (int ks = 0; ks < 2; ++ks)
    koff[ks] = cl * 64 + ((((ks << 2) + hi) ^ key7) << 3);
  const int pwc   = hi >> 1;
  const int pwoff = (hi & 1) << 2;
  int pwch[4];
  #pragma unroll
  for (int n = 0; n < 4; ++n)
    pwch[n] = ((((n << 1) + pwc) ^ key7) << 3) + pwoff + cl * 64;

  const floatx4 fzero = {0.f, 0.f, 0.f, 0.f};
  floatx4 o[2][4];
  floatx4 ol[2];
  floatx4 s[4][2];
  short8 vones;
  #pragma unroll
  for (int j = 0; j < 8; ++j) vones[j] = (short)0x3F80;
  #pragma unroll
  for (int tt = 0; tt < 2; ++tt) {
    ol[tt] = fzero;
    #pragma unroll
    for (int nd = 0; nd < 4; ++nd) o[tt][nd] = fzero;
  }

  const int c0    = w << 1;
  const int srow8 = lane >> 3;
  const int gch8  = (((lane & 7) ^ srow8) << 3);
  const short* kbase = k_ws + (size_t)(b * 4096 + (c0 << 3) + srow8) * 1024 + h * 64 + gch8;
  const short* vbase = vt_ws + ((size_t)bh * 64 + (c0 << 3) + srow8) * 4096 + gch8;

  auto stage = [&](int buf, int kv0) {
    gl_lds16(kbase + (size_t)kv0 * 1024,          (void*)&Ks[buf][c0 * 512]);
    gl_lds16(kbase + (size_t)kv0 * 1024 + 8192,   (void*)&Ks[buf][(c0 + 1) * 512]);
    gl_lds16(vbase + kv0,                          (void*)&Vts[buf][c0 * 512]);
    gl_lds16(vbase + kv0 + 8 * 4096,               (void*)&Vts[buf][(c0 + 1) * 512]);
  };

  auto qk = [&](const short* kb) {
    short8 kf[2][4];
    #pragma unroll
    for (int ks = 0; ks < 2; ++ks)
      #pragma unroll
      for (int n = 0; n < 4; ++n)
        kf[ks][n] = *reinterpret_cast<const short8*>(kb + koff[ks] + n * 1024);
    #pragma unroll
    for (int n = 0; n < 4; ++n)
      #pragma unroll
      for (int tt = 0; tt < 2; ++tt)
        s[n][tt] = __builtin_amdgcn_mfma_f32_16x16x32_bf16(
            kf[1][n], qf[tt][1],
            __builtin_amdgcn_mfma_f32_16x16x32_bf16(kf[0][n], qf[tt][0], fzero, 0, 0, 0),
            0, 0, 0);
  };
  auto pv = [&](const short* plb, const short* vb) {
    #pragma unroll
    for (int ks = 0; ks < 2; ++ks) {
      short8 pa[2], vf[4];
      #pragma unroll
      for (int tt = 0; tt < 2; ++tt)
        pa[tt] = *reinterpret_cast<const short8*>(plb + koff[ks] + tt * 1024);
      #pragma unroll
      for (int nd = 0; nd < 4; ++nd)
        vf[nd] = *reinterpret_cast<const short8*>(vb + koff[ks] + nd * 1024);
      #pragma unroll
      for (int tt = 0; tt < 2; ++tt) {
        ol[tt] = __builtin_amdgcn_mfma_f32_16x16x32_bf16(pa[tt], vones, ol[tt], 0, 0, 0);
        #pragma unroll
        for (int nd = 0; nd < 4; ++nd)
          o[tt][nd] = __builtin_amdgcn_mfma_f32_16x16x32_bf16(pa[tt], vf[nd], o[tt][nd], 0, 0, 0);
      }
    }
  };
  auto smax = [&](short* plw) {
    #pragma unroll
    for (int tt = 0; tt < 2; ++tt)
      #pragma unroll
      for (int n = 0; n < 4; ++n) {
        short4 pk;
        #pragma unroll
        for (int ii = 0; ii < 4; ++ii)
          pk[ii] = f2bf(EXP2(s[n][tt][ii]));
        *reinterpret_cast<short4*>(plw + tt * 1024 + pwch[n]) = pk;
      }
  };

  stage(0, 0);
  WAIT_VM(0); BAR(); FENCE();
  qk(&Ks[0][0]);
  stage(1, 64);
  smax(&Pl[w][0]);

  for (int t = 0; t < 63; ++t) {
    const int cur = t & 1;
    WAIT_VM(0); BAR(); FENCE();
    __builtin_amdgcn_s_setprio(1);
    qk(&Ks[cur ^ 1][0]);
    pv(&Pl[w][0], &Vts[cur][0]);
    __builtin_amdgcn_s_setprio(0);
    FENCE(); BAR();
    stage(cur, ((t + 2) & 63) << 6);
    WAIT_LGKM0();
    smax(&Pl[w][0]);
  }
  __builtin_amdgcn_s_setprio(1);
  pv(&Pl[w][0], &Vts[1][0]);
  __builtin_amdgcn_s_setprio(0);
  WAIT_VM(0);

  #pragma unroll
  for (int m = 0; m < 2; ++m) {
    float inv[4];
    #pragma unroll
    for (int ii = 0; ii < 4; ++ii)
      inv[ii] = 1.f / ol[m][ii];
    #pragma unroll
    for (int nd = 0; nd < 4; ++nd)
      #pragma unroll
      for (int ii = 0; ii < 4; ++ii) {
        size_t idx = (size_t)(b * 1024 + q0 + m * 16 + rq + ii) * 1024
                   + h * 64 + nd * 16 + cl;
        ao_ws[idx] = f2bf(o[m][nd][ii] * inv[ii]);
      }
  }
}

extern "C" void kernel_launch(void* const* d_in, const int* in_sizes, int n_in,
                              void* d_out, int out_size, void* d_ws, size_t ws_size,
                              hipStream_t stream)
{
  const float* x     = (const float*)d_in[0];
  const float* query = (const float*)d_in[1];
  const float* Wq    = (const float*)d_in[2];
  const float* Wkv   = (const float*)d_in[3];
  const float* Wproj = (const float*)d_in[4];
  const float* bproj = (const float*)d_in[5];
  float* out = (float*)d_out;

  const float QSCALE = 0.18033688011112042f;  // (1/sqrt(64)) * log2(e)

  char* ws = (char*)d_ws;
  short* k_ws   = (short*)(ws);
  short* vt_ws  = (short*)(ws + (32ull << 20));
  short* xb     = (short*)(ws + (64ull << 20));   // dead after kv gemm
  short* q_ws   = (short*)(ws + (72ull << 20));   // overlaps xb tail (safe: q written after)
  short* ao_ws  = (short*)(ws + (80ull << 20));
  short* wkvb   = (short*)(ws + (96ull << 20));
  short* wqb    = (short*)(ws + (100ull << 20));
  short* wprojb = (short*)(ws + (102ull << 20));

  conv_weights<<<dim3(2048), 256, 0, stream>>>(Wkv, Wq, Wproj, wkvb, wqb, wprojb);
  f32_to_bf16<<<dim3(8192), 256, 0, stream>>>(x, xb, (16384 * 1024) / 8);

  gemm256_kv<<<dim3(512), 512, 0, stream>>>(xb, wkvb, k_ws, vt_ws,
                                            16384, 2048, 1024);
  // q = (query @ Wq^T) * QSCALE  (query fp32 read directly — no conv kernel)
  gemm64<0, true><<<dim3(1024), 256, 0, stream>>>(query, wqb, q_ws, nullptr,
                                                  4096, 1024, 1024, QSCALE);
  attn_fwd<<<dim3(512), 256, 0, stream>>>(q_ws, k_ws, vt_ws, ao_ws);
  gemm64<2, false><<<dim3(1024), 256, 0, stream>>>(ao_ws, wprojb, out, bproj,
                                                   4096, 1024, 1024, 1.0f);
}

// Round 18
// 208.912 us; speedup vs baseline: 1.3481x; 1.0291x over previous
//
#include <hip/hip_runtime.h>
#include <hip/hip_bf16.h>

typedef __attribute__((ext_vector_type(8))) short short8;
typedef __attribute__((ext_vector_type(4))) float floatx4;

#if __has_builtin(__builtin_amdgcn_exp2f)
#define EXP2(x) __builtin_amdgcn_exp2f(x)
#else
#define EXP2(x) exp2f(x)
#endif

#define BAR() __builtin_amdgcn_s_barrier()
#define FENCE() asm volatile("" ::: "memory")
#define WAIT_LGKM0() asm volatile("s_waitcnt lgkmcnt(0)" ::: "memory")
#define WAIT_VM(n) asm volatile("s_waitcnt vmcnt(" #n ")" ::: "memory")

__device__ __forceinline__ short f2bf(float f) {
  __hip_bfloat16 h = __float2bfloat16(f);
  return *reinterpret_cast<const short*>(&h);
}

__device__ __forceinline__ short8 cvt_f32x8_bf16(const float* __restrict__ p) {
  float4 a = *reinterpret_cast<const float4*>(p);
  float4 b = *reinterpret_cast<const float4*>(p + 4);
  short8 r;
  r[0] = f2bf(a.x); r[1] = f2bf(a.y); r[2] = f2bf(a.z); r[3] = f2bf(a.w);
  r[4] = f2bf(b.x); r[5] = f2bf(b.y); r[6] = f2bf(b.z); r[7] = f2bf(b.w);
  return r;
}

typedef const __attribute__((address_space(1))) void* gptr1;
typedef __attribute__((address_space(3))) void* lptr3;
__device__ __forceinline__ void gl_lds16(const void* g, void* l) {
  __builtin_amdgcn_global_load_lds((gptr1)g, (lptr3)l, 16, 0, 0);
}

// ---------------- fp32 -> bf16 conversion (memory-bound) ----------------
__global__ __launch_bounds__(256)
void f32_to_bf16(const float* __restrict__ in, short* __restrict__ out, int n8) {
  int i = blockIdx.x * blockDim.x + threadIdx.x;
  if (i < n8) {
    short8 v = cvt_f32x8_bf16(in + (size_t)i * 8);
    *reinterpret_cast<short8*>(out + (size_t)i * 8) = v;
  }
}

// fused 3-weight conversion
__global__ __launch_bounds__(256)
void conv_weights(const float* __restrict__ Wkv, const float* __restrict__ Wq,
                  const float* __restrict__ Wproj, short* __restrict__ wkvb,
                  short* __restrict__ wqb, short* __restrict__ wprojb) {
  const float* src; short* dst; int off;
  int i = blockIdx.x * 256 + threadIdx.x;
  if (blockIdx.x < 1024)      { src = Wkv;   dst = wkvb;   off = i; }
  else if (blockIdx.x < 1536) { src = Wq;    dst = wqb;    off = i - 1024 * 256; }
  else                        { src = Wproj; dst = wprojb; off = i - 1536 * 256; }
  short8 v = cvt_f32x8_bf16(src + (size_t)off * 8);
  *reinterpret_cast<short8*>(dst + (size_t)off * 8) = v;
}

// ============ 256x256 8-phase GEMM for kv (round-15, measured ~81 µs) ====
__global__ __launch_bounds__(512, 2)
void gemm256_kv(const short* __restrict__ A, const short* __restrict__ B,
                short* __restrict__ k_out, short* __restrict__ vt,
                int M, int N, int K)
{
  __shared__ __align__(16) short lds[2][2][2][128 * 64]; // [parity][A/B][slot][row*64]

  const int tid  = threadIdx.x;
  const int lane = tid & 63;
  const int w    = tid >> 6;
  const int wm   = w >> 2;
  const int wn   = w & 3;
  const int cl   = lane & 15;
  const int hi   = lane >> 4;
  const int srl  = lane >> 3;
  const int gch8 = (((lane & 7) ^ srl) << 3);

  const int ntile = N >> 8;
  int bid = blockIdx.x;
  { int cpx = gridDim.x >> 3; bid = (bid & 7) * cpx + (bid >> 3); }
  const int tm = bid / ntile, tn = bid % ntile;
  const int m0 = tm << 8, n0 = tn << 8;
  const int NT = K >> 6;

  auto stageA = [&](int par, int slot, int ktX) {
    #pragma unroll
    for (int j = 0; j < 2; ++j) {
      const int sr = (w << 4) + (j << 3) + srl;
      const int tr = ((sr >> 6) << 7) + (slot << 6) + (sr & 63);
      gl_lds16(A + (size_t)(m0 + tr) * K + ktX + gch8,
               (void*)&lds[par][0][slot][((w << 4) + (j << 3)) * 64]);
    }
  };
  auto stageB = [&](int par, int slot, int ktX) {
    #pragma unroll
    for (int j = 0; j < 2; ++j) {
      const int sr = (w << 4) + (j << 3) + srl;
      const int tr = ((sr >> 5) << 6) + (slot << 5) + (sr & 31);
      gl_lds16(B + (size_t)(n0 + tr) * K + ktX + gch8,
               (void*)&lds[par][1][slot][((w << 4) + (j << 3)) * 64]);
    }
  };

  const floatx4 fzero = {0.f, 0.f, 0.f, 0.f};
  floatx4 acc[8][4];
  #pragma unroll
  for (int m = 0; m < 8; ++m)
    #pragma unroll
    for (int n = 0; n < 4; ++n)
      acc[m][n] = fzero;

  short8 af[4][2], b0[2][2], b1[2][2];

  auto readA = [&](int par, int slot) {
    #pragma unroll
    for (int m = 0; m < 4; ++m)
      #pragma unroll
      for (int ks = 0; ks < 2; ++ks) {
        const int sr = (wm << 6) + (m << 4) + cl;
        const int cpos = ((((ks << 2) + hi) ^ (sr & 7)) << 3);
        af[m][ks] = *reinterpret_cast<const short8*>(&lds[par][0][slot][sr * 64 + cpos]);
      }
  };
  auto readB = [&](int par, int slot, short8 (&bf)[2][2]) {
    #pragma unroll
    for (int n = 0; n < 2; ++n)
      #pragma unroll
      for (int ks = 0; ks < 2; ++ks) {
        const int sr = (wn << 5) + (n << 4) + cl;
        const int cpos = ((((ks << 2) + hi) ^ (sr & 7)) << 3);
        bf[n][ks] = *reinterpret_cast<const short8*>(&lds[par][1][slot][sr * 64 + cpos]);
      }
  };

  #define QUAD(BF, MH, NH)                                                     \
    __builtin_amdgcn_s_setprio(1);                                             \
    _Pragma("unroll")                                                          \
    for (int ks = 0; ks < 2; ++ks)                                             \
      _Pragma("unroll")                                                        \
      for (int m = 0; m < 4; ++m)                                              \
        _Pragma("unroll")                                                      \
        for (int n = 0; n < 2; ++n)                                            \
          acc[(MH)*4 + m][(NH)*2 + n] = __builtin_amdgcn_mfma_f32_16x16x32_bf16( \
              af[m][ks], BF[n][ks], acc[(MH)*4 + m][(NH)*2 + n], 0, 0, 0);     \
    __builtin_amdgcn_s_setprio(0);

  stageA(0, 0, 0); stageB(0, 0, 0); stageB(0, 1, 0); stageA(0, 1, 0);
  stageA(1, 0, 64); stageB(1, 0, 64); stageB(1, 1, 64);
  WAIT_VM(6); BAR(); FENCE();

  for (int t = 0; t < NT; ++t) {
    const int p  = t & 1;
    const int pn = p ^ 1;
    int t1 = t + 1; if (t1 >= NT) t1 -= NT;
    int t2 = t + 2; if (t2 >= NT) t2 -= NT;
    const int kt1 = t1 << 6;
    const int kt2 = t2 << 6;

    readA(p, 0); readB(p, 0, b0);
    stageA(pn, 1, kt1);
    BAR(); WAIT_LGKM0();
    QUAD(b0, 0, 0);
    BAR(); FENCE();

    readB(p, 1, b1);
    stageA(p, 0, kt2);
    BAR(); WAIT_LGKM0();
    QUAD(b1, 0, 1);
    BAR(); FENCE();

    readA(p, 1);
    stageB(p, 0, kt2);
    BAR(); WAIT_LGKM0();
    QUAD(b0, 1, 0);
    BAR(); FENCE();

    stageB(p, 1, kt2);
    WAIT_VM(6);
    BAR(); WAIT_LGKM0();
    QUAD(b1, 1, 1);
    BAR(); FENCE();
  }
  WAIT_VM(0);

  const int rq = hi << 2;
  #pragma unroll
  for (int Mi = 0; Mi < 8; ++Mi) {
    #pragma unroll
    for (int Nn = 0; Nn < 4; ++Nn) {
      const int grow = m0 + wm * 128 + Mi * 16 + rq;
      const int gcol = n0 + wn * 64 + Nn * 16 + cl;
      if (gcol < 1024) {
        #pragma unroll
        for (int i = 0; i < 4; ++i)
          k_out[(size_t)(grow + i) * 1024 + gcol] = f2bf(acc[Mi][Nn][i]);
      } else {
        const int d  = gcol - 1024;
        const int bb = grow >> 12;
        const int nn = grow & 4095;
        size_t base = ((size_t)(bb * 16 + (d >> 6)) * 64 + (d & 63)) * 4096 + nn;
        short4 pk;
        pk.x = f2bf(acc[Mi][Nn][0]); pk.y = f2bf(acc[Mi][Nn][1]);
        pk.z = f2bf(acc[Mi][Nn][2]); pk.w = f2bf(acc[Mi][Nn][3]);
        *reinterpret_cast<short4*>(&vt[base]) = pk;
      }
    }
  }
}

// ---------------- 64x64-tile GEMM for skinny projections (round-15) ------
template<int MODE>
__global__ __launch_bounds__(256, 4)
void gemm64(const short* __restrict__ A, const short* __restrict__ B,
            void* __restrict__ O0, const float* __restrict__ bias,
            int M, int N, int K, float oscale)
{
  __shared__ __align__(16) short As[64 * 64];
  __shared__ __align__(16) short Bs[64 * 64];

  const int tid  = threadIdx.x;
  const int lane = tid & 63;
  const int w    = tid >> 6;
  const int ntile = N >> 6;
  int bid = blockIdx.x;
  { int cpx = gridDim.x >> 3; bid = (bid & 7) * cpx + (bid >> 3); }
  const int tm = bid / ntile;
  const int tn = bid % ntile;
  const int m0 = tm << 6, n0 = tn << 6;
  const int wr = (w >> 1) << 5;
  const int wc = (w & 1) << 5;
  const int cl = lane & 15;
  const int hi = lane >> 4;
  const int srow = lane >> 3;
  const int scol = (lane & 7) << 3;

  const floatx4 fzero = {0.f, 0.f, 0.f, 0.f};
  floatx4 acc[2][2];
  #pragma unroll
  for (int m = 0; m < 2; ++m)
    #pragma unroll
    for (int n = 0; n < 2; ++n)
      acc[m][n] = fzero;

  for (int kt = 0; kt < K; kt += 64) {
    #pragma unroll
    for (int i = 0; i < 2; ++i) {
      const int chunk = (w << 1) + i;
      const int row   = (chunk << 3) + srow;
      gl_lds16(A + (size_t)(m0 + row) * K + kt + scol, &As[chunk * 512]);
      gl_lds16(B + (size_t)(n0 + row) * K + kt + scol, &Bs[chunk * 512]);
    }
    __syncthreads();

    #pragma unroll
    for (int ks = 0; ks < 2; ++ks) {
      short8 af[2], bfr[2];
      #pragma unroll
      for (int m = 0; m < 2; ++m)
        af[m] = *reinterpret_cast<const short8*>(
            &As[(wr + m * 16 + cl) * 64 + ks * 32 + (hi << 3)]);
      #pragma unroll
      for (int n = 0; n < 2; ++n)
        bfr[n] = *reinterpret_cast<const short8*>(
            &Bs[(wc + n * 16 + cl) * 64 + ks * 32 + (hi << 3)]);
      #pragma unroll
      for (int m = 0; m < 2; ++m)
        #pragma unroll
        for (int n = 0; n < 2; ++n)
          acc[m][n] = __builtin_amdgcn_mfma_f32_16x16x32_bf16(af[m], bfr[n], acc[m][n], 0, 0, 0);
    }
    __syncthreads();
  }

  const int rq = hi << 2;
  #pragma unroll
  for (int m = 0; m < 2; ++m) {
    #pragma unroll
    for (int n = 0; n < 2; ++n) {
      const int grow = m0 + wr + m * 16 + rq;
      const int gcol = n0 + wc + n * 16 + cl;
      if (MODE == 0) {
        short* o = (short*)O0;
        #pragma unroll
        for (int i = 0; i < 4; ++i)
          o[(size_t)(grow + i) * N + gcol] = f2bf(acc[m][n][i] * oscale);
      } else {
        float* o = (float*)O0;
        const float bv = bias[gcol];
        #pragma unroll
        for (int i = 0; i < 4; ++i)
          o[(size_t)(grow + i) * N + gcol] = acc[m][n][i] + bv;
      }
    }
  }
}

// ---------------- flash attention: 3-ring, ONE barrier per iteration -----
// 4 waves x 32 q-rows, grid 512. Stage stays AFTER the burst (round-10's
// failure was stage-before-burst contention, not the ring). Safety: a wave
// past the top barrier has issued its previous-iter PV MFMAs, so the
// ds_reads on the ring slot being overwritten have retired. Pl is per-wave
// and same-wave LDS ops execute in order -> no lgkm drain needed.
__global__ __launch_bounds__(256, 2)
void attn_fwd(const short* __restrict__ q_ws, const short* __restrict__ k_ws,
              const short* __restrict__ vt_ws, short* __restrict__ ao_ws)
{
  __shared__ __align__(16) short Ks[3][64 * 64];
  __shared__ __align__(16) short Vts[3][64 * 64];
  __shared__ __align__(16) short Pl[4][32 * 64];

  const int tid  = threadIdx.x;
  const int lane = tid & 63;
  const int w    = tid >> 6;
  const int i    = blockIdx.x;
  const int bh   = (i & 7) * 8 + (i >> 6);   // same bh -> same i%8 -> same XCD
  const int qt   = (i >> 3) & 7;
  const int b  = bh >> 4;
  const int h  = bh & 15;
  const int q0 = qt * 128 + w * 32;
  const int cl = lane & 15;
  const int hi = lane >> 4;
  const int rq = hi << 2;
  const int key7 = cl & 7;

  short8 qf[2][2];
  #pragma unroll
  for (int tt = 0; tt < 2; ++tt)
    #pragma unroll
    for (int ks = 0; ks < 2; ++ks) {
      size_t idx = (size_t)(b * 1024 + q0 + tt * 16 + cl) * 1024
                 + h * 64 + ks * 32 + (hi << 3);
      qf[tt][ks] = *reinterpret_cast<const short8*>(&q_ws[idx]);
    }

  int koff[2];
  #pragma unroll
  for (int ks = 0; ks < 2; ++ks)
    koff[ks] = cl * 64 + ((((ks << 2) + hi) ^ key7) << 3);
  const int pwc   = hi >> 1;
  const int pwoff = (hi & 1) << 2;
  int pwch[4];
  #pragma unroll
  for (int n = 0; n < 4; ++n)
    pwch[n] = ((((n << 1) + pwc) ^ key7) << 3) + pwoff + cl * 64;

  const floatx4 fzero = {0.f, 0.f, 0.f, 0.f};
  floatx4 o[2][4];
  floatx4 ol[2];
  floatx4 s[4][2];
  short8 vones;
  #pragma unroll
  for (int j = 0; j < 8; ++j) vones[j] = (short)0x3F80;  // bf16 1.0
  #pragma unroll
  for (int tt = 0; tt < 2; ++tt) {
    ol[tt] = fzero;
    #pragma unroll
    for (int nd = 0; nd < 4; ++nd) o[tt][nd] = fzero;
  }

  const int c0    = w << 1;
  const int srow8 = lane >> 3;
  const int gch8  = (((lane & 7) ^ srow8) << 3);
  const short* kbase = k_ws + (size_t)(b * 4096 + (c0 << 3) + srow8) * 1024 + h * 64 + gch8;
  const short* vbase = vt_ws + ((size_t)bh * 64 + (c0 << 3) + srow8) * 4096 + gch8;

  auto stage = [&](int buf, int kv0) {
    gl_lds16(kbase + (size_t)kv0 * 1024,          (void*)&Ks[buf][c0 * 512]);
    gl_lds16(kbase + (size_t)kv0 * 1024 + 8192,   (void*)&Ks[buf][(c0 + 1) * 512]);
    gl_lds16(vbase + kv0,                          (void*)&Vts[buf][c0 * 512]);
    gl_lds16(vbase + kv0 + 8 * 4096,               (void*)&Vts[buf][(c0 + 1) * 512]);
  };

  auto qk = [&](const short* kb) {            // writes s fresh (zero C on ks=0)
    short8 kf[2][4];
    #pragma unroll
    for (int ks = 0; ks < 2; ++ks)
      #pragma unroll
      for (int n = 0; n < 4; ++n)
        kf[ks][n] = *reinterpret_cast<const short8*>(kb + koff[ks] + n * 1024);
    #pragma unroll
    for (int n = 0; n < 4; ++n)
      #pragma unroll
      for (int tt = 0; tt < 2; ++tt)
        s[n][tt] = __builtin_amdgcn_mfma_f32_16x16x32_bf16(
            kf[1][n], qf[tt][1],
            __builtin_amdgcn_mfma_f32_16x16x32_bf16(kf[0][n], qf[tt][0], fzero, 0, 0, 0),
            0, 0, 0);
  };
  auto pv = [&](const short* plb, const short* vb) {
    #pragma unroll
    for (int ks = 0; ks < 2; ++ks) {
      short8 pa[2], vf[4];
      #pragma unroll
      for (int tt = 0; tt < 2; ++tt)
        pa[tt] = *reinterpret_cast<const short8*>(plb + koff[ks] + tt * 1024);
      #pragma unroll
      for (int nd = 0; nd < 4; ++nd)
        vf[nd] = *reinterpret_cast<const short8*>(vb + koff[ks] + nd * 1024);
      #pragma unroll
      for (int tt = 0; tt < 2; ++tt) {
        ol[tt] = __builtin_amdgcn_mfma_f32_16x16x32_bf16(pa[tt], vones, ol[tt], 0, 0, 0);
        #pragma unroll
        for (int nd = 0; nd < 4; ++nd)
          o[tt][nd] = __builtin_amdgcn_mfma_f32_16x16x32_bf16(pa[tt], vf[nd], o[tt][nd], 0, 0, 0);
      }
    }
  };
  auto smax = [&](short* plw) {
    #pragma unroll
    for (int tt = 0; tt < 2; ++tt)
      #pragma unroll
      for (int n = 0; n < 4; ++n) {
        short4 pk;
        #pragma unroll
        for (int ii = 0; ii < 4; ++ii)
          pk[ii] = f2bf(EXP2(s[n][tt][ii]));
        *reinterpret_cast<short4*>(plw + tt * 1024 + pwch[n]) = pk;
      }
  };

  // ---- prologue: stage 0,1 -> QK(0) -> softmax(0)
  stage(0, 0);
  stage(1, 64);
  WAIT_VM(4); BAR(); FENCE();     // tile 0 landed (stage(1) still in flight)
  qk(&Ks[0][0]);
  smax(&Pl[w][0]);
  int i0 = 0, i1 = 1, i2 = 2;

  // ---- main loop: ONE barrier per iteration
  for (int t = 0; t < 63; ++t) {
    WAIT_VM(0); BAR(); FENCE();          // tile t+1 landed for all waves
    __builtin_amdgcn_s_setprio(1);
    qk(&Ks[i1][0]);                      // K[t+1] (fresh s)
    pv(&Pl[w][0], &Vts[i0][0]);          // P[t] x V[t] + ones row-sum
    __builtin_amdgcn_s_setprio(0);
    stage(i2, ((t + 2) & 63) << 6);      // ring slot last read at iter t-1
    smax(&Pl[w][0]);                     // P[t+1] (per-wave, in-order LDS)
    int tmp = i0; i0 = i1; i1 = i2; i2 = tmp;
  }
  // ---- epilogue: PV(63); V[63] in buf i0, landed by iter-62's wait
  __builtin_amdgcn_s_setprio(1);
  pv(&Pl[w][0], &Vts[i0][0]);
  __builtin_amdgcn_s_setprio(0);
  WAIT_VM(0);

  // finalize: ol[m][ii] = l[q = m*16 + rq + ii] exactly -> no shuffles
  #pragma unroll
  for (int m = 0; m < 2; ++m) {
    float inv[4];
    #pragma unroll
    for (int ii = 0; ii < 4; ++ii)
      inv[ii] = 1.f / ol[m][ii];
    #pragma unroll
    for (int nd = 0; nd < 4; ++nd)
      #pragma unroll
      for (int ii = 0; ii < 4; ++ii) {
        size_t idx = (size_t)(b * 1024 + q0 + m * 16 + rq + ii) * 1024
                   + h * 64 + nd * 16 + cl;
        ao_ws[idx] = f2bf(o[m][nd][ii] * inv[ii]);
      }
  }
}

extern "C" void kernel_launch(void* const* d_in, const int* in_sizes, int n_in,
                              void* d_out, int out_size, void* d_ws, size_t ws_size,
                              hipStream_t stream)
{
  const float* x     = (const float*)d_in[0];
  const float* query = (const float*)d_in[1];
  const float* Wq    = (const float*)d_in[2];
  const float* Wkv   = (const float*)d_in[3];
  const float* Wproj = (const float*)d_in[4];
  const float* bproj = (const float*)d_in[5];
  float* out = (float*)d_out;

  const float QSCALE = 0.18033688011112042f;  // (1/sqrt(64)) * log2(e)

  char* ws = (char*)d_ws;
  short* k_ws   = (short*)(ws);
  short* vt_ws  = (short*)(ws + (32ull << 20));
  short* xb     = (short*)(ws + (64ull << 20));
  short* qb     = (short*)(ws + (64ull << 20));
  short* q_ws   = (short*)(ws + (72ull << 20));
  short* ao_ws  = (short*)(ws + (80ull << 20));
  short* wkvb   = (short*)(ws + (96ull << 20));
  short* wqb    = (short*)(ws + (100ull << 20));
  short* wprojb = (short*)(ws + (102ull << 20));

  conv_weights<<<dim3(2048), 256, 0, stream>>>(Wkv, Wq, Wproj, wkvb, wqb, wprojb);
  f32_to_bf16<<<dim3(8192), 256, 0, stream>>>(x, xb, (16384 * 1024) / 8);

  gemm256_kv<<<dim3(512), 512, 0, stream>>>(xb, wkvb, k_ws, vt_ws,
                                            16384, 2048, 1024);
  f32_to_bf16<<<dim3(2048), 256, 0, stream>>>(query, qb, (4096 * 1024) / 8);
  gemm64<0><<<dim3(1024), 256, 0, stream>>>(qb, wqb, q_ws, nullptr,
                                            4096, 1024, 1024, QSCALE);
  attn_fwd<<<dim3(512), 256, 0, stream>>>(q_ws, k_ws, vt_ws, ao_ws);
  gemm64<2><<<dim3(1024), 256, 0, stream>>>(ao_ws, wprojb, out, bproj,
                                            4096, 1024, 1024, 1.0f);
}

// Round 19
// 208.888 us; speedup vs baseline: 1.3482x; 1.0001x over previous
//
#include <hip/hip_runtime.h>
#include <hip/hip_bf16.h>

typedef __attribute__((ext_vector_type(8))) short short8;
typedef __attribute__((ext_vector_type(4))) float floatx4;

#if __has_builtin(__builtin_amdgcn_exp2f)
#define EXP2(x) __builtin_amdgcn_exp2f(x)
#else
#define EXP2(x) exp2f(x)
#endif

#define BAR() __builtin_amdgcn_s_barrier()
#define FENCE() asm volatile("" ::: "memory")
#define WAIT_LGKM0() asm volatile("s_waitcnt lgkmcnt(0)" ::: "memory")
#define WAIT_VM(n) asm volatile("s_waitcnt vmcnt(" #n ")" ::: "memory")

__device__ __forceinline__ short f2bf(float f) {
  __hip_bfloat16 h = __float2bfloat16(f);
  return *reinterpret_cast<const short*>(&h);
}

__device__ __forceinline__ short8 cvt_f32x8_bf16(const float* __restrict__ p) {
  float4 a = *reinterpret_cast<const float4*>(p);
  float4 b = *reinterpret_cast<const float4*>(p + 4);
  short8 r;
  r[0] = f2bf(a.x); r[1] = f2bf(a.y); r[2] = f2bf(a.z); r[3] = f2bf(a.w);
  r[4] = f2bf(b.x); r[5] = f2bf(b.y); r[6] = f2bf(b.z); r[7] = f2bf(b.w);
  return r;
}

typedef const __attribute__((address_space(1))) void* gptr1;
typedef __attribute__((address_space(3))) void* lptr3;
__device__ __forceinline__ void gl_lds16(const void* g, void* l) {
  __builtin_amdgcn_global_load_lds((gptr1)g, (lptr3)l, 16, 0, 0);
}

// ---------------- fp32 -> bf16 conversion (memory-bound) ----------------
__global__ __launch_bounds__(256)
void f32_to_bf16(const float* __restrict__ in, short* __restrict__ out, int n8) {
  int i = blockIdx.x * blockDim.x + threadIdx.x;
  if (i < n8) {
    short8 v = cvt_f32x8_bf16(in + (size_t)i * 8);
    *reinterpret_cast<short8*>(out + (size_t)i * 8) = v;
  }
}

// fused 3-weight conversion
__global__ __launch_bounds__(256)
void conv_weights(const float* __restrict__ Wkv, const float* __restrict__ Wq,
                  const float* __restrict__ Wproj, short* __restrict__ wkvb,
                  short* __restrict__ wqb, short* __restrict__ wprojb) {
  const float* src; short* dst; int off;
  int i = blockIdx.x * 256 + threadIdx.x;
  if (blockIdx.x < 1024)      { src = Wkv;   dst = wkvb;   off = i; }
  else if (blockIdx.x < 1536) { src = Wq;    dst = wqb;    off = i - 1024 * 256; }
  else                        { src = Wproj; dst = wprojb; off = i - 1536 * 256; }
  short8 v = cvt_f32x8_bf16(src + (size_t)off * 8);
  *reinterpret_cast<short8*>(dst + (size_t)off * 8) = v;
}

// ============ 256x256 8-phase GEMM for kv (round-15, measured ~81 µs) ====
__global__ __launch_bounds__(512, 2)
void gemm256_kv(const short* __restrict__ A, const short* __restrict__ B,
                short* __restrict__ k_out, short* __restrict__ vt,
                int M, int N, int K)
{
  __shared__ __align__(16) short lds[2][2][2][128 * 64]; // [parity][A/B][slot][row*64]

  const int tid  = threadIdx.x;
  const int lane = tid & 63;
  const int w    = tid >> 6;
  const int wm   = w >> 2;
  const int wn   = w & 3;
  const int cl   = lane & 15;
  const int hi   = lane >> 4;
  const int srl  = lane >> 3;
  const int gch8 = (((lane & 7) ^ srl) << 3);

  const int ntile = N >> 8;
  int bid = blockIdx.x;
  { int cpx = gridDim.x >> 3; bid = (bid & 7) * cpx + (bid >> 3); }
  const int tm = bid / ntile, tn = bid % ntile;
  const int m0 = tm << 8, n0 = tn << 8;
  const int NT = K >> 6;

  auto stageA = [&](int par, int slot, int ktX) {
    #pragma unroll
    for (int j = 0; j < 2; ++j) {
      const int sr = (w << 4) + (j << 3) + srl;
      const int tr = ((sr >> 6) << 7) + (slot << 6) + (sr & 63);
      gl_lds16(A + (size_t)(m0 + tr) * K + ktX + gch8,
               (void*)&lds[par][0][slot][((w << 4) + (j << 3)) * 64]);
    }
  };
  auto stageB = [&](int par, int slot, int ktX) {
    #pragma unroll
    for (int j = 0; j < 2; ++j) {
      const int sr = (w << 4) + (j << 3) + srl;
      const int tr = ((sr >> 5) << 6) + (slot << 5) + (sr & 31);
      gl_lds16(B + (size_t)(n0 + tr) * K + ktX + gch8,
               (void*)&lds[par][1][slot][((w << 4) + (j << 3)) * 64]);
    }
  };

  const floatx4 fzero = {0.f, 0.f, 0.f, 0.f};
  floatx4 acc[8][4];
  #pragma unroll
  for (int m = 0; m < 8; ++m)
    #pragma unroll
    for (int n = 0; n < 4; ++n)
      acc[m][n] = fzero;

  short8 af[4][2], b0[2][2], b1[2][2];

  auto readA = [&](int par, int slot) {
    #pragma unroll
    for (int m = 0; m < 4; ++m)
      #pragma unroll
      for (int ks = 0; ks < 2; ++ks) {
        const int sr = (wm << 6) + (m << 4) + cl;
        const int cpos = ((((ks << 2) + hi) ^ (sr & 7)) << 3);
        af[m][ks] = *reinterpret_cast<const short8*>(&lds[par][0][slot][sr * 64 + cpos]);
      }
  };
  auto readB = [&](int par, int slot, short8 (&bf)[2][2]) {
    #pragma unroll
    for (int n = 0; n < 2; ++n)
      #pragma unroll
      for (int ks = 0; ks < 2; ++ks) {
        const int sr = (wn << 5) + (n << 4) + cl;
        const int cpos = ((((ks << 2) + hi) ^ (sr & 7)) << 3);
        bf[n][ks] = *reinterpret_cast<const short8*>(&lds[par][1][slot][sr * 64 + cpos]);
      }
  };

  #define QUAD(BF, MH, NH)                                                     \
    __builtin_amdgcn_s_setprio(1);                                             \
    _Pragma("unroll")                                                          \
    for (int ks = 0; ks < 2; ++ks)                                             \
      _Pragma("unroll")                                                        \
      for (int m = 0; m < 4; ++m)                                              \
        _Pragma("unroll")                                                      \
        for (int n = 0; n < 2; ++n)                                            \
          acc[(MH)*4 + m][(NH)*2 + n] = __builtin_amdgcn_mfma_f32_16x16x32_bf16( \
              af[m][ks], BF[n][ks], acc[(MH)*4 + m][(NH)*2 + n], 0, 0, 0);     \
    __builtin_amdgcn_s_setprio(0);

  stageA(0, 0, 0); stageB(0, 0, 0); stageB(0, 1, 0); stageA(0, 1, 0);
  stageA(1, 0, 64); stageB(1, 0, 64); stageB(1, 1, 64);
  WAIT_VM(6); BAR(); FENCE();

  for (int t = 0; t < NT; ++t) {
    const int p  = t & 1;
    const int pn = p ^ 1;
    int t1 = t + 1; if (t1 >= NT) t1 -= NT;
    int t2 = t + 2; if (t2 >= NT) t2 -= NT;
    const int kt1 = t1 << 6;
    const int kt2 = t2 << 6;

    readA(p, 0); readB(p, 0, b0);
    stageA(pn, 1, kt1);
    BAR(); WAIT_LGKM0();
    QUAD(b0, 0, 0);
    BAR(); FENCE();

    readB(p, 1, b1);
    stageA(p, 0, kt2);
    BAR(); WAIT_LGKM0();
    QUAD(b1, 0, 1);
    BAR(); FENCE();

    readA(p, 1);
    stageB(p, 0, kt2);
    BAR(); WAIT_LGKM0();
    QUAD(b0, 1, 0);
    BAR(); FENCE();

    stageB(p, 1, kt2);
    WAIT_VM(6);
    BAR(); WAIT_LGKM0();
    QUAD(b1, 1, 1);
    BAR(); FENCE();
  }
  WAIT_VM(0);

  const int rq = hi << 2;
  #pragma unroll
  for (int Mi = 0; Mi < 8; ++Mi) {
    #pragma unroll
    for (int Nn = 0; Nn < 4; ++Nn) {
      const int grow = m0 + wm * 128 + Mi * 16 + rq;
      const int gcol = n0 + wn * 64 + Nn * 16 + cl;
      if (gcol < 1024) {
        #pragma unroll
        for (int i = 0; i < 4; ++i)
          k_out[(size_t)(grow + i) * 1024 + gcol] = f2bf(acc[Mi][Nn][i]);
      } else {
        const int d  = gcol - 1024;
        const int bb = grow >> 12;
        const int nn = grow & 4095;
        size_t base = ((size_t)(bb * 16 + (d >> 6)) * 64 + (d & 63)) * 4096 + nn;
        short4 pk;
        pk.x = f2bf(acc[Mi][Nn][0]); pk.y = f2bf(acc[Mi][Nn][1]);
        pk.z = f2bf(acc[Mi][Nn][2]); pk.w = f2bf(acc[Mi][Nn][3]);
        *reinterpret_cast<short4*>(&vt[base]) = pk;
      }
    }
  }
}

// ---------------- 64x64-tile GEMM for skinny projections (round-15) ------
template<int MODE>
__global__ __launch_bounds__(256, 4)
void gemm64(const short* __restrict__ A, const short* __restrict__ B,
            void* __restrict__ O0, const float* __restrict__ bias,
            int M, int N, int K, float oscale)
{
  __shared__ __align__(16) short As[64 * 64];
  __shared__ __align__(16) short Bs[64 * 64];

  const int tid  = threadIdx.x;
  const int lane = tid & 63;
  const int w    = tid >> 6;
  const int ntile = N >> 6;
  int bid = blockIdx.x;
  { int cpx = gridDim.x >> 3; bid = (bid & 7) * cpx + (bid >> 3); }
  const int tm = bid / ntile;
  const int tn = bid % ntile;
  const int m0 = tm << 6, n0 = tn << 6;
  const int wr = (w >> 1) << 5;
  const int wc = (w & 1) << 5;
  const int cl = lane & 15;
  const int hi = lane >> 4;
  const int srow = lane >> 3;
  const int scol = (lane & 7) << 3;

  const floatx4 fzero = {0.f, 0.f, 0.f, 0.f};
  floatx4 acc[2][2];
  #pragma unroll
  for (int m = 0; m < 2; ++m)
    #pragma unroll
    for (int n = 0; n < 2; ++n)
      acc[m][n] = fzero;

  for (int kt = 0; kt < K; kt += 64) {
    #pragma unroll
    for (int i = 0; i < 2; ++i) {
      const int chunk = (w << 1) + i;
      const int row   = (chunk << 3) + srow;
      gl_lds16(A + (size_t)(m0 + row) * K + kt + scol, &As[chunk * 512]);
      gl_lds16(B + (size_t)(n0 + row) * K + kt + scol, &Bs[chunk * 512]);
    }
    __syncthreads();

    #pragma unroll
    for (int ks = 0; ks < 2; ++ks) {
      short8 af[2], bfr[2];
      #pragma unroll
      for (int m = 0; m < 2; ++m)
        af[m] = *reinterpret_cast<const short8*>(
            &As[(wr + m * 16 + cl) * 64 + ks * 32 + (hi << 3)]);
      #pragma unroll
      for (int n = 0; n < 2; ++n)
        bfr[n] = *reinterpret_cast<const short8*>(
            &Bs[(wc + n * 16 + cl) * 64 + ks * 32 + (hi << 3)]);
      #pragma unroll
      for (int m = 0; m < 2; ++m)
        #pragma unroll
        for (int n = 0; n < 2; ++n)
          acc[m][n] = __builtin_amdgcn_mfma_f32_16x16x32_bf16(af[m], bfr[n], acc[m][n], 0, 0, 0);
    }
    __syncthreads();
  }

  const int rq = hi << 2;
  #pragma unroll
  for (int m = 0; m < 2; ++m) {
    #pragma unroll
    for (int n = 0; n < 2; ++n) {
      const int grow = m0 + wr + m * 16 + rq;
      const int gcol = n0 + wc + n * 16 + cl;
      if (MODE == 0) {
        short* o = (short*)O0;
        #pragma unroll
        for (int i = 0; i < 4; ++i)
          o[(size_t)(grow + i) * N + gcol] = f2bf(acc[m][n][i] * oscale);
      } else {
        float* o = (float*)O0;
        const float bv = bias[gcol];
        #pragma unroll
        for (int i = 0; i < 4; ++i)
          o[(size_t)(grow + i) * N + gcol] = acc[m][n][i] + bv;
      }
    }
  }
}

// ---------------- flash attention: 4-ring + counted vmcnt(4) -------------
// 4 waves x 32 q-rows, grid 512. One barrier/iter; stage AFTER the burst
// (proven placement) for tile t+3 -> wait distance = full iteration.
// At top of iter t: outstanding = stage(t+2)+stage(t+3 prev); WAIT_VM(4)
// retires stage(t+1)... (in-order: retires oldest = tile t+1's 4 loads).
// Slot (t+3)&3 last read (V[t-1]) before barrier(t) -> write-safe.
__global__ __launch_bounds__(256, 2)
void attn_fwd(const short* __restrict__ q_ws, const short* __restrict__ k_ws,
              const short* __restrict__ vt_ws, short* __restrict__ ao_ws)
{
  __shared__ __align__(16) short Ks[4][64 * 64];
  __shared__ __align__(16) short Vts[4][64 * 64];
  __shared__ __align__(16) short Pl[4][32 * 64];

  const int tid  = threadIdx.x;
  const int lane = tid & 63;
  const int w    = tid >> 6;
  const int i    = blockIdx.x;
  const int bh   = (i & 7) * 8 + (i >> 6);   // same bh -> same i%8 -> same XCD
  const int qt   = (i >> 3) & 7;
  const int b  = bh >> 4;
  const int h  = bh & 15;
  const int q0 = qt * 128 + w * 32;
  const int cl = lane & 15;
  const int hi = lane >> 4;
  const int rq = hi << 2;
  const int key7 = cl & 7;

  short8 qf[2][2];
  #pragma unroll
  for (int tt = 0; tt < 2; ++tt)
    #pragma unroll
    for (int ks = 0; ks < 2; ++ks) {
      size_t idx = (size_t)(b * 1024 + q0 + tt * 16 + cl) * 1024
                 + h * 64 + ks * 32 + (hi << 3);
      qf[tt][ks] = *reinterpret_cast<const short8*>(&q_ws[idx]);
    }

  int koff[2];
  #pragma unroll
  for (int ks = 0; ks < 2; ++ks)
    koff[ks] = cl * 64 + ((((ks << 2) + hi) ^ key7) << 3);
  const int pwc   = hi >> 1;
  const int pwoff = (hi & 1) << 2;
  int pwch[4];
  #pragma unroll
  for (int n = 0; n < 4; ++n)
    pwch[n] = ((((n << 1) + pwc) ^ key7) << 3) + pwoff + cl * 64;

  const floatx4 fzero = {0.f, 0.f, 0.f, 0.f};
  floatx4 o[2][4];
  floatx4 ol[2];
  floatx4 s[4][2];
  short8 vones;
  #pragma unroll
  for (int j = 0; j < 8; ++j) vones[j] = (short)0x3F80;  // bf16 1.0
  #pragma unroll
  for (int tt = 0; tt < 2; ++tt) {
    ol[tt] = fzero;
    #pragma unroll
    for (int nd = 0; nd < 4; ++nd) o[tt][nd] = fzero;
  }

  const int c0    = w << 1;
  const int srow8 = lane >> 3;
  const int gch8  = (((lane & 7) ^ srow8) << 3);
  const short* kbase = k_ws + (size_t)(b * 4096 + (c0 << 3) + srow8) * 1024 + h * 64 + gch8;
  const short* vbase = vt_ws + ((size_t)bh * 64 + (c0 << 3) + srow8) * 4096 + gch8;

  auto stage = [&](int buf, int kv0) {
    gl_lds16(kbase + (size_t)kv0 * 1024,          (void*)&Ks[buf][c0 * 512]);
    gl_lds16(kbase + (size_t)kv0 * 1024 + 8192,   (void*)&Ks[buf][(c0 + 1) * 512]);
    gl_lds16(vbase + kv0,                          (void*)&Vts[buf][c0 * 512]);
    gl_lds16(vbase + kv0 + 8 * 4096,               (void*)&Vts[buf][(c0 + 1) * 512]);
  };

  auto qk = [&](const short* kb) {            // writes s fresh (zero C on ks=0)
    short8 kf[2][4];
    #pragma unroll
    for (int ks = 0; ks < 2; ++ks)
      #pragma unroll
      for (int n = 0; n < 4; ++n)
        kf[ks][n] = *reinterpret_cast<const short8*>(kb + koff[ks] + n * 1024);
    #pragma unroll
    for (int n = 0; n < 4; ++n)
      #pragma unroll
      for (int tt = 0; tt < 2; ++tt)
        s[n][tt] = __builtin_amdgcn_mfma_f32_16x16x32_bf16(
            kf[1][n], qf[tt][1],
            __builtin_amdgcn_mfma_f32_16x16x32_bf16(kf[0][n], qf[tt][0], fzero, 0, 0, 0),
            0, 0, 0);
  };
  auto pv = [&](const short* plb, const short* vb) {
    #pragma unroll
    for (int ks = 0; ks < 2; ++ks) {
      short8 pa[2], vf[4];
      #pragma unroll
      for (int tt = 0; tt < 2; ++tt)
        pa[tt] = *reinterpret_cast<const short8*>(plb + koff[ks] + tt * 1024);
      #pragma unroll
      for (int nd = 0; nd < 4; ++nd)
        vf[nd] = *reinterpret_cast<const short8*>(vb + koff[ks] + nd * 1024);
      #pragma unroll
      for (int tt = 0; tt < 2; ++tt) {
        ol[tt] = __builtin_amdgcn_mfma_f32_16x16x32_bf16(pa[tt], vones, ol[tt], 0, 0, 0);
        #pragma unroll
        for (int nd = 0; nd < 4; ++nd)
          o[tt][nd] = __builtin_amdgcn_mfma_f32_16x16x32_bf16(pa[tt], vf[nd], o[tt][nd], 0, 0, 0);
      }
    }
  };
  auto smax = [&](short* plw) {
    #pragma unroll
    for (int tt = 0; tt < 2; ++tt)
      #pragma unroll
      for (int n = 0; n < 4; ++n) {
        short4 pk;
        #pragma unroll
        for (int ii = 0; ii < 4; ++ii)
          pk[ii] = f2bf(EXP2(s[n][tt][ii]));
        *reinterpret_cast<short4*>(plw + tt * 1024 + pwch[n]) = pk;
      }
  };

  // ---- prologue: stage 0,1,2 -> QK(0) -> softmax(0)
  stage(0, 0);
  stage(1, 64);
  stage(2, 128);
  WAIT_VM(8); BAR(); FENCE();     // qf + tile 0 landed; tiles 1,2 in flight
  qk(&Ks[0][0]);
  smax(&Pl[w][0]);

  // ---- main loop: one barrier/iter; counted vmcnt keeps 1 extra tile in flight
  for (int t = 0; t < 63; ++t) {
    WAIT_VM(4); BAR(); FENCE();          // tile t+1 landed; tile t+2 in flight
    __builtin_amdgcn_s_setprio(1);
    qk(&Ks[(t + 1) & 3][0]);             // K[t+1] (fresh s)
    pv(&Pl[w][0], &Vts[t & 3][0]);       // P[t] x V[t] + ones row-sum
    __builtin_amdgcn_s_setprio(0);
    stage((t + 3) & 3, ((t + 3) & 63) << 6);  // slot last read at iter t-1
    smax(&Pl[w][0]);                     // P[t+1]
  }
  // ---- epilogue: PV(63); V[63] (slot 3) landed at iter 62's wait
  __builtin_amdgcn_s_setprio(1);
  pv(&Pl[w][0], &Vts[3][0]);
  __builtin_amdgcn_s_setprio(0);
  WAIT_VM(0);

  // finalize: ol[m][ii] = l[q = m*16 + rq + ii] exactly -> no shuffles
  #pragma unroll
  for (int m = 0; m < 2; ++m) {
    float inv[4];
    #pragma unroll
    for (int ii = 0; ii < 4; ++ii)
      inv[ii] = 1.f / ol[m][ii];
    #pragma unroll
    for (int nd = 0; nd < 4; ++nd)
      #pragma unroll
      for (int ii = 0; ii < 4; ++ii) {
        size_t idx = (size_t)(b * 1024 + q0 + m * 16 + rq + ii) * 1024
                   + h * 64 + nd * 16 + cl;
        ao_ws[idx] = f2bf(o[m][nd][ii] * inv[ii]);
      }
  }
}

extern "C" void kernel_launch(void* const* d_in, const int* in_sizes, int n_in,
                              void* d_out, int out_size, void* d_ws, size_t ws_size,
                              hipStream_t stream)
{
  const float* x     = (const float*)d_in[0];
  const float* query = (const float*)d_in[1];
  const float* Wq    = (const float*)d_in[2];
  const float* Wkv   = (const float*)d_in[3];
  const float* Wproj = (const float*)d_in[4];
  const float* bproj = (const float*)d_in[5];
  float* out = (float*)d_out;

  const float QSCALE = 0.18033688011112042f;  // (1/sqrt(64)) * log2(e)

  char* ws = (char*)d_ws;
  short* k_ws   = (short*)(ws);
  short* vt_ws  = (short*)(ws + (32ull << 20));
  short* xb     = (short*)(ws + (64ull << 20));
  short* qb     = (short*)(ws + (64ull << 20));
  short* q_ws   = (short*)(ws + (72ull << 20));
  short* ao_ws  = (short*)(ws + (80ull << 20));
  short* wkvb   = (short*)(ws + (96ull << 20));
  short* wqb    = (short*)(ws + (100ull << 20));
  short* wprojb = (short*)(ws + (102ull << 20));

  conv_weights<<<dim3(2048), 256, 0, stream>>>(Wkv, Wq, Wproj, wkvb, wqb, wprojb);
  f32_to_bf16<<<dim3(8192), 256, 0, stream>>>(x, xb, (16384 * 1024) / 8);

  gemm256_kv<<<dim3(512), 512, 0, stream>>>(xb, wkvb, k_ws, vt_ws,
                                            16384, 2048, 1024);
  f32_to_bf16<<<dim3(2048), 256, 0, stream>>>(query, qb, (4096 * 1024) / 8);
  gemm64<0><<<dim3(1024), 256, 0, stream>>>(qb, wqb, q_ws, nullptr,
                                            4096, 1024, 1024, QSCALE);
  attn_fwd<<<dim3(512), 256, 0, stream>>>(q_ws, k_ws, vt_ws, ao_ws);
  gemm64<2><<<dim3(1024), 256, 0, stream>>>(ao_ws, wprojb, out, bproj,
                                            4096, 1024, 1024, 1.0f);
}

// Round 20
// 207.028 us; speedup vs baseline: 1.3604x; 1.0090x over previous
//
#include <hip/hip_runtime.h>
#include <hip/hip_bf16.h>

typedef __attribute__((ext_vector_type(8))) short short8;
typedef __attribute__((ext_vector_type(4))) float floatx4;

#if __has_builtin(__builtin_amdgcn_exp2f)
#define EXP2(x) __builtin_amdgcn_exp2f(x)
#else
#define EXP2(x) exp2f(x)
#endif

#define BAR() __builtin_amdgcn_s_barrier()
#define FENCE() asm volatile("" ::: "memory")
#define WAIT_LGKM0() asm volatile("s_waitcnt lgkmcnt(0)" ::: "memory")
#define WAIT_VM(n) asm volatile("s_waitcnt vmcnt(" #n ")" ::: "memory")

__device__ __forceinline__ short f2bf(float f) {
  __hip_bfloat16 h = __float2bfloat16(f);
  return *reinterpret_cast<const short*>(&h);
}

__device__ __forceinline__ short8 cvt_f32x8_bf16(const float* __restrict__ p) {
  float4 a = *reinterpret_cast<const float4*>(p);
  float4 b = *reinterpret_cast<const float4*>(p + 4);
  short8 r;
  r[0] = f2bf(a.x); r[1] = f2bf(a.y); r[2] = f2bf(a.z); r[3] = f2bf(a.w);
  r[4] = f2bf(b.x); r[5] = f2bf(b.y); r[6] = f2bf(b.z); r[7] = f2bf(b.w);
  return r;
}

typedef const __attribute__((address_space(1))) void* gptr1;
typedef __attribute__((address_space(3))) void* lptr3;
__device__ __forceinline__ void gl_lds16(const void* g, void* l) {
  __builtin_amdgcn_global_load_lds((gptr1)g, (lptr3)l, 16, 0, 0);
}

// ---------------- fp32 -> bf16 conversion (memory-bound) ----------------
__global__ __launch_bounds__(256)
void f32_to_bf16(const float* __restrict__ in, short* __restrict__ out, int n8) {
  int i = blockIdx.x * blockDim.x + threadIdx.x;
  if (i < n8) {
    short8 v = cvt_f32x8_bf16(in + (size_t)i * 8);
    *reinterpret_cast<short8*>(out + (size_t)i * 8) = v;
  }
}

// fused conversion: x (8192 blocks) + Wkv (1024) + Wq (512) + Wproj (512)
__global__ __launch_bounds__(256)
void conv_all(const float* __restrict__ x, const float* __restrict__ Wkv,
              const float* __restrict__ Wq, const float* __restrict__ Wproj,
              short* __restrict__ xb, short* __restrict__ wkvb,
              short* __restrict__ wqb, short* __restrict__ wprojb) {
  const float* src; short* dst; size_t off;
  int bi = blockIdx.x;
  size_t i = (size_t)bi * 256 + threadIdx.x;
  if (bi < 8192)      { src = x;     dst = xb;     off = i; }
  else if (bi < 9216) { src = Wkv;   dst = wkvb;   off = i - (size_t)8192 * 256; }
  else if (bi < 9728) { src = Wq;    dst = wqb;    off = i - (size_t)9216 * 256; }
  else                { src = Wproj; dst = wprojb; off = i - (size_t)9728 * 256; }
  short8 v = cvt_f32x8_bf16(src + off * 8);
  *reinterpret_cast<short8*>(dst + off * 8) = v;
}

// ============ 256x256 8-phase GEMM for kv (measured ~81 µs) ====
__global__ __launch_bounds__(512, 2)
void gemm256_kv(const short* __restrict__ A, const short* __restrict__ B,
                short* __restrict__ k_out, short* __restrict__ vt,
                int M, int N, int K)
{
  __shared__ __align__(16) short lds[2][2][2][128 * 64]; // [parity][A/B][slot][row*64]

  const int tid  = threadIdx.x;
  const int lane = tid & 63;
  const int w    = tid >> 6;
  const int wm   = w >> 2;
  const int wn   = w & 3;
  const int cl   = lane & 15;
  const int hi   = lane >> 4;
  const int srl  = lane >> 3;
  const int gch8 = (((lane & 7) ^ srl) << 3);

  const int ntile = N >> 8;
  int bid = blockIdx.x;
  { int cpx = gridDim.x >> 3; bid = (bid & 7) * cpx + (bid >> 3); }
  const int tm = bid / ntile, tn = bid % ntile;
  const int m0 = tm << 8, n0 = tn << 8;
  const int NT = K >> 6;

  auto stageA = [&](int par, int slot, int ktX) {
    #pragma unroll
    for (int j = 0; j < 2; ++j) {
      const int sr = (w << 4) + (j << 3) + srl;
      const int tr = ((sr >> 6) << 7) + (slot << 6) + (sr & 63);
      gl_lds16(A + (size_t)(m0 + tr) * K + ktX + gch8,
               (void*)&lds[par][0][slot][((w << 4) + (j << 3)) * 64]);
    }
  };
  auto stageB = [&](int par, int slot, int ktX) {
    #pragma unroll
    for (int j = 0; j < 2; ++j) {
      const int sr = (w << 4) + (j << 3) + srl;
      const int tr = ((sr >> 5) << 6) + (slot << 5) + (sr & 31);
      gl_lds16(B + (size_t)(n0 + tr) * K + ktX + gch8,
               (void*)&lds[par][1][slot][((w << 4) + (j << 3)) * 64]);
    }
  };

  const floatx4 fzero = {0.f, 0.f, 0.f, 0.f};
  floatx4 acc[8][4];
  #pragma unroll
  for (int m = 0; m < 8; ++m)
    #pragma unroll
    for (int n = 0; n < 4; ++n)
      acc[m][n] = fzero;

  short8 af[4][2], b0[2][2], b1[2][2];

  auto readA = [&](int par, int slot) {
    #pragma unroll
    for (int m = 0; m < 4; ++m)
      #pragma unroll
      for (int ks = 0; ks < 2; ++ks) {
        const int sr = (wm << 6) + (m << 4) + cl;
        const int cpos = ((((ks << 2) + hi) ^ (sr & 7)) << 3);
        af[m][ks] = *reinterpret_cast<const short8*>(&lds[par][0][slot][sr * 64 + cpos]);
      }
  };
  auto readB = [&](int par, int slot, short8 (&bf)[2][2]) {
    #pragma unroll
    for (int n = 0; n < 2; ++n)
      #pragma unroll
      for (int ks = 0; ks < 2; ++ks) {
        const int sr = (wn << 5) + (n << 4) + cl;
        const int cpos = ((((ks << 2) + hi) ^ (sr & 7)) << 3);
        bf[n][ks] = *reinterpret_cast<const short8*>(&lds[par][1][slot][sr * 64 + cpos]);
      }
  };

  #define QUAD(BF, MH, NH)                                                     \
    __builtin_amdgcn_s_setprio(1);                                             \
    _Pragma("unroll")                                                          \
    for (int ks = 0; ks < 2; ++ks)                                             \
      _Pragma("unroll")                                                        \
      for (int m = 0; m < 4; ++m)                                              \
        _Pragma("unroll")                                                      \
        for (int n = 0; n < 2; ++n)                                            \
          acc[(MH)*4 + m][(NH)*2 + n] = __builtin_amdgcn_mfma_f32_16x16x32_bf16( \
              af[m][ks], BF[n][ks], acc[(MH)*4 + m][(NH)*2 + n], 0, 0, 0);     \
    __builtin_amdgcn_s_setprio(0);

  stageA(0, 0, 0); stageB(0, 0, 0); stageB(0, 1, 0); stageA(0, 1, 0);
  stageA(1, 0, 64); stageB(1, 0, 64); stageB(1, 1, 64);
  WAIT_VM(6); BAR(); FENCE();

  for (int t = 0; t < NT; ++t) {
    const int p  = t & 1;
    const int pn = p ^ 1;
    int t1 = t + 1; if (t1 >= NT) t1 -= NT;
    int t2 = t + 2; if (t2 >= NT) t2 -= NT;
    const int kt1 = t1 << 6;
    const int kt2 = t2 << 6;

    readA(p, 0); readB(p, 0, b0);
    stageA(pn, 1, kt1);
    BAR(); WAIT_LGKM0();
    QUAD(b0, 0, 0);
    BAR(); FENCE();

    readB(p, 1, b1);
    stageA(p, 0, kt2);
    BAR(); WAIT_LGKM0();
    QUAD(b1, 0, 1);
    BAR(); FENCE();

    readA(p, 1);
    stageB(p, 0, kt2);
    BAR(); WAIT_LGKM0();
    QUAD(b0, 1, 0);
    BAR(); FENCE();

    stageB(p, 1, kt2);
    WAIT_VM(6);
    BAR(); WAIT_LGKM0();
    QUAD(b1, 1, 1);
    BAR(); FENCE();
  }
  WAIT_VM(0);

  const int rq = hi << 2;
  #pragma unroll
  for (int Mi = 0; Mi < 8; ++Mi) {
    #pragma unroll
    for (int Nn = 0; Nn < 4; ++Nn) {
      const int grow = m0 + wm * 128 + Mi * 16 + rq;
      const int gcol = n0 + wn * 64 + Nn * 16 + cl;
      if (gcol < 1024) {
        #pragma unroll
        for (int i = 0; i < 4; ++i)
          k_out[(size_t)(grow + i) * 1024 + gcol] = f2bf(acc[Mi][Nn][i]);
      } else {
        const int d  = gcol - 1024;
        const int bb = grow >> 12;
        const int nn = grow & 4095;
        size_t base = ((size_t)(bb * 16 + (d >> 6)) * 64 + (d & 63)) * 4096 + nn;
        short4 pk;
        pk.x = f2bf(acc[Mi][Nn][0]); pk.y = f2bf(acc[Mi][Nn][1]);
        pk.z = f2bf(acc[Mi][Nn][2]); pk.w = f2bf(acc[Mi][Nn][3]);
        *reinterpret_cast<short4*>(&vt[base]) = pk;
      }
    }
  }
}

// ---------------- 64x64-tile GEMM for skinny projections ------
template<int MODE>
__global__ __launch_bounds__(256, 4)
void gemm64(const short* __restrict__ A, const short* __restrict__ B,
            void* __restrict__ O0, const float* __restrict__ bias,
            int M, int N, int K, float oscale)
{
  __shared__ __align__(16) short As[64 * 64];
  __shared__ __align__(16) short Bs[64 * 64];

  const int tid  = threadIdx.x;
  const int lane = tid & 63;
  const int w    = tid >> 6;
  const int ntile = N >> 6;
  int bid = blockIdx.x;
  { int cpx = gridDim.x >> 3; bid = (bid & 7) * cpx + (bid >> 3); }
  const int tm = bid / ntile;
  const int tn = bid % ntile;
  const int m0 = tm << 6, n0 = tn << 6;
  const int wr = (w >> 1) << 5;
  const int wc = (w & 1) << 5;
  const int cl = lane & 15;
  const int hi = lane >> 4;
  const int srow = lane >> 3;
  const int scol = (lane & 7) << 3;

  const floatx4 fzero = {0.f, 0.f, 0.f, 0.f};
  floatx4 acc[2][2];
  #pragma unroll
  for (int m = 0; m < 2; ++m)
    #pragma unroll
    for (int n = 0; n < 2; ++n)
      acc[m][n] = fzero;

  for (int kt = 0; kt < K; kt += 64) {
    #pragma unroll
    for (int i = 0; i < 2; ++i) {
      const int chunk = (w << 1) + i;
      const int row   = (chunk << 3) + srow;
      gl_lds16(A + (size_t)(m0 + row) * K + kt + scol, &As[chunk * 512]);
      gl_lds16(B + (size_t)(n0 + row) * K + kt + scol, &Bs[chunk * 512]);
    }
    __syncthreads();

    #pragma unroll
    for (int ks = 0; ks < 2; ++ks) {
      short8 af[2], bfr[2];
      #pragma unroll
      for (int m = 0; m < 2; ++m)
        af[m] = *reinterpret_cast<const short8*>(
            &As[(wr + m * 16 + cl) * 64 + ks * 32 + (hi << 3)]);
      #pragma unroll
      for (int n = 0; n < 2; ++n)
        bfr[n] = *reinterpret_cast<const short8*>(
            &Bs[(wc + n * 16 + cl) * 64 + ks * 32 + (hi << 3)]);
      #pragma unroll
      for (int m = 0; m < 2; ++m)
        #pragma unroll
        for (int n = 0; n < 2; ++n)
          acc[m][n] = __builtin_amdgcn_mfma_f32_16x16x32_bf16(af[m], bfr[n], acc[m][n], 0, 0, 0);
    }
    __syncthreads();
  }

  const int rq = hi << 2;
  #pragma unroll
  for (int m = 0; m < 2; ++m) {
    #pragma unroll
    for (int n = 0; n < 2; ++n) {
      const int grow = m0 + wr + m * 16 + rq;
      const int gcol = n0 + wc + n * 16 + cl;
      if (MODE == 0) {
        short* o = (short*)O0;
        #pragma unroll
        for (int i = 0; i < 4; ++i)
          o[(size_t)(grow + i) * N + gcol] = f2bf(acc[m][n][i] * oscale);
      } else {
        float* o = (float*)O0;
        const float bv = bias[gcol];
        #pragma unroll
        for (int i = 0; i < 4; ++i)
          o[(size_t)(grow + i) * N + gcol] = acc[m][n][i] + bv;
      }
    }
  }
}

// ---------------- flash attention: 4-ring + counted vmcnt(4) (~81 µs) ----
__global__ __launch_bounds__(256, 2)
void attn_fwd(const short* __restrict__ q_ws, const short* __restrict__ k_ws,
              const short* __restrict__ vt_ws, short* __restrict__ ao_ws)
{
  __shared__ __align__(16) short Ks[4][64 * 64];
  __shared__ __align__(16) short Vts[4][64 * 64];
  __shared__ __align__(16) short Pl[4][32 * 64];

  const int tid  = threadIdx.x;
  const int lane = tid & 63;
  const int w    = tid >> 6;
  const int i    = blockIdx.x;
  const int bh   = (i & 7) * 8 + (i >> 6);   // same bh -> same i%8 -> same XCD
  const int qt   = (i >> 3) & 7;
  const int b  = bh >> 4;
  const int h  = bh & 15;
  const int q0 = qt * 128 + w * 32;
  const int cl = lane & 15;
  const int hi = lane >> 4;
  const int rq = hi << 2;
  const int key7 = cl & 7;

  short8 qf[2][2];
  #pragma unroll
  for (int tt = 0; tt < 2; ++tt)
    #pragma unroll
    for (int ks = 0; ks < 2; ++ks) {
      size_t idx = (size_t)(b * 1024 + q0 + tt * 16 + cl) * 1024
                 + h * 64 + ks * 32 + (hi << 3);
      qf[tt][ks] = *reinterpret_cast<const short8*>(&q_ws[idx]);
    }

  int koff[2];
  #pragma unroll
  for (int ks = 0; ks < 2; ++ks)
    koff[ks] = cl * 64 + ((((ks << 2) + hi) ^ key7) << 3);
  const int pwc   = hi >> 1;
  const int pwoff = (hi & 1) << 2;
  int pwch[4];
  #pragma unroll
  for (int n = 0; n < 4; ++n)
    pwch[n] = ((((n << 1) + pwc) ^ key7) << 3) + pwoff + cl * 64;

  const floatx4 fzero = {0.f, 0.f, 0.f, 0.f};
  floatx4 o[2][4];
  floatx4 ol[2];
  floatx4 s[4][2];
  short8 vones;
  #pragma unroll
  for (int j = 0; j < 8; ++j) vones[j] = (short)0x3F80;  // bf16 1.0
  #pragma unroll
  for (int tt = 0; tt < 2; ++tt) {
    ol[tt] = fzero;
    #pragma unroll
    for (int nd = 0; nd < 4; ++nd) o[tt][nd] = fzero;
  }

  const int c0    = w << 1;
  const int srow8 = lane >> 3;
  const int gch8  = (((lane & 7) ^ srow8) << 3);
  const short* kbase = k_ws + (size_t)(b * 4096 + (c0 << 3) + srow8) * 1024 + h * 64 + gch8;
  const short* vbase = vt_ws + ((size_t)bh * 64 + (c0 << 3) + srow8) * 4096 + gch8;

  auto stage = [&](int buf, int kv0) {
    gl_lds16(kbase + (size_t)kv0 * 1024,          (void*)&Ks[buf][c0 * 512]);
    gl_lds16(kbase + (size_t)kv0 * 1024 + 8192,   (void*)&Ks[buf][(c0 + 1) * 512]);
    gl_lds16(vbase + kv0,                          (void*)&Vts[buf][c0 * 512]);
    gl_lds16(vbase + kv0 + 8 * 4096,               (void*)&Vts[buf][(c0 + 1) * 512]);
  };

  auto qk = [&](const short* kb) {            // writes s fresh (zero C on ks=0)
    short8 kf[2][4];
    #pragma unroll
    for (int ks = 0; ks < 2; ++ks)
      #pragma unroll
      for (int n = 0; n < 4; ++n)
        kf[ks][n] = *reinterpret_cast<const short8*>(kb + koff[ks] + n * 1024);
    #pragma unroll
    for (int n = 0; n < 4; ++n)
      #pragma unroll
      for (int tt = 0; tt < 2; ++tt)
        s[n][tt] = __builtin_amdgcn_mfma_f32_16x16x32_bf16(
            kf[1][n], qf[tt][1],
            __builtin_amdgcn_mfma_f32_16x16x32_bf16(kf[0][n], qf[tt][0], fzero, 0, 0, 0),
            0, 0, 0);
  };
  auto pv = [&](const short* plb, const short* vb) {
    #pragma unroll
    for (int ks = 0; ks < 2; ++ks) {
      short8 pa[2], vf[4];
      #pragma unroll
      for (int tt = 0; tt < 2; ++tt)
        pa[tt] = *reinterpret_cast<const short8*>(plb + koff[ks] + tt * 1024);
      #pragma unroll
      for (int nd = 0; nd < 4; ++nd)
        vf[nd] = *reinterpret_cast<const short8*>(vb + koff[ks] + nd * 1024);
      #pragma unroll
      for (int tt = 0; tt < 2; ++tt) {
        ol[tt] = __builtin_amdgcn_mfma_f32_16x16x32_bf16(pa[tt], vones, ol[tt], 0, 0, 0);
        #pragma unroll
        for (int nd = 0; nd < 4; ++nd)
          o[tt][nd] = __builtin_amdgcn_mfma_f32_16x16x32_bf16(pa[tt], vf[nd], o[tt][nd], 0, 0, 0);
      }
    }
  };
  auto smax = [&](short* plw) {
    #pragma unroll
    for (int tt = 0; tt < 2; ++tt)
      #pragma unroll
      for (int n = 0; n < 4; ++n) {
        short4 pk;
        #pragma unroll
        for (int ii = 0; ii < 4; ++ii)
          pk[ii] = f2bf(EXP2(s[n][tt][ii]));
        *reinterpret_cast<short4*>(plw + tt * 1024 + pwch[n]) = pk;
      }
  };

  // ---- prologue: stage 0,1,2 -> QK(0) -> softmax(0)
  stage(0, 0);
  stage(1, 64);
  stage(2, 128);
  WAIT_VM(8); BAR(); FENCE();     // qf + tile 0 landed; tiles 1,2 in flight
  qk(&Ks[0][0]);
  smax(&Pl[w][0]);

  // ---- main loop: one barrier/iter; counted vmcnt keeps 1 extra tile in flight
  for (int t = 0; t < 63; ++t) {
    WAIT_VM(4); BAR(); FENCE();          // tile t+1 landed; tile t+2 in flight
    __builtin_amdgcn_s_setprio(1);
    qk(&Ks[(t + 1) & 3][0]);             // K[t+1] (fresh s)
    pv(&Pl[w][0], &Vts[t & 3][0]);       // P[t] x V[t] + ones row-sum
    __builtin_amdgcn_s_setprio(0);
    stage((t + 3) & 3, ((t + 3) & 63) << 6);  // slot last read at iter t-1
    smax(&Pl[w][0]);                     // P[t+1]
  }
  // ---- epilogue: PV(63); V[63] (slot 3) landed at iter 62's wait
  __builtin_amdgcn_s_setprio(1);
  pv(&Pl[w][0], &Vts[3][0]);
  __builtin_amdgcn_s_setprio(0);
  WAIT_VM(0);

  // finalize: ol[m][ii] = l[q = m*16 + rq + ii] exactly -> no shuffles
  #pragma unroll
  for (int m = 0; m < 2; ++m) {
    float inv[4];
    #pragma unroll
    for (int ii = 0; ii < 4; ++ii)
      inv[ii] = 1.f / ol[m][ii];
    #pragma unroll
    for (int nd = 0; nd < 4; ++nd)
      #pragma unroll
      for (int ii = 0; ii < 4; ++ii) {
        size_t idx = (size_t)(b * 1024 + q0 + m * 16 + rq + ii) * 1024
                   + h * 64 + nd * 16 + cl;
        ao_ws[idx] = f2bf(o[m][nd][ii] * inv[ii]);
      }
  }
}

extern "C" void kernel_launch(void* const* d_in, const int* in_sizes, int n_in,
                              void* d_out, int out_size, void* d_ws, size_t ws_size,
                              hipStream_t stream)
{
  const float* x     = (const float*)d_in[0];
  const float* query = (const float*)d_in[1];
  const float* Wq    = (const float*)d_in[2];
  const float* Wkv   = (const float*)d_in[3];
  const float* Wproj = (const float*)d_in[4];
  const float* bproj = (const float*)d_in[5];
  float* out = (float*)d_out;

  const float QSCALE = 0.18033688011112042f;  // (1/sqrt(64)) * log2(e)

  char* ws = (char*)d_ws;
  short* k_ws   = (short*)(ws);
  short* vt_ws  = (short*)(ws + (32ull << 20));
  short* xb     = (short*)(ws + (64ull << 20));   // dead after kv gemm
  short* qb     = (short*)(ws + (64ull << 20));   // written after kv gemm
  short* q_ws   = (short*)(ws + (72ull << 20));
  short* ao_ws  = (short*)(ws + (80ull << 20));
  short* wkvb   = (short*)(ws + (96ull << 20));
  short* wqb    = (short*)(ws + (100ull << 20));
  short* wprojb = (short*)(ws + (102ull << 20));

  // fused: x + all 3 weights in one dispatch
  conv_all<<<dim3(10240), 256, 0, stream>>>(x, Wkv, Wq, Wproj,
                                            xb, wkvb, wqb, wprojb);
  gemm256_kv<<<dim3(512), 512, 0, stream>>>(xb, wkvb, k_ws, vt_ws,
                                            16384, 2048, 1024);
  f32_to_bf16<<<dim3(2048), 256, 0, stream>>>(query, qb, (4096 * 1024) / 8);
  gemm64<0><<<dim3(1024), 256, 0, stream>>>(qb, wqb, q_ws, nullptr,
                                            4096, 1024, 1024, QSCALE);
  attn_fwd<<<dim3(512), 256, 0, stream>>>(q_ws, k_ws, vt_ws, ao_ws);
  gemm64<2><<<dim3(1024), 256, 0, stream>>>(ao_ws, wprojb, out, bproj,
                                            4096, 1024, 1024, 1.0f);
}

// Round 21
// 204.827 us; speedup vs baseline: 1.3750x; 1.0107x over previous
//
#include <hip/hip_runtime.h>
#include <hip/hip_bf16.h>

typedef __attribute__((ext_vector_type(8))) short short8;
typedef __attribute__((ext_vector_type(4))) float floatx4;

#if __has_builtin(__builtin_amdgcn_exp2f)
#define EXP2(x) __builtin_amdgcn_exp2f(x)
#else
#define EXP2(x) exp2f(x)
#endif

#define BAR() __builtin_amdgcn_s_barrier()
#define FENCE() asm volatile("" ::: "memory")
#define WAIT_LGKM0() asm volatile("s_waitcnt lgkmcnt(0)" ::: "memory")
#define WAIT_VM(n) asm volatile("s_waitcnt vmcnt(" #n ")" ::: "memory")

__device__ __forceinline__ short f2bf(float f) {
  __hip_bfloat16 h = __float2bfloat16(f);
  return *reinterpret_cast<const short*>(&h);
}

__device__ __forceinline__ short8 cvt_f32x8_bf16(const float* __restrict__ p) {
  float4 a = *reinterpret_cast<const float4*>(p);
  float4 b = *reinterpret_cast<const float4*>(p + 4);
  short8 r;
  r[0] = f2bf(a.x); r[1] = f2bf(a.y); r[2] = f2bf(a.z); r[3] = f2bf(a.w);
  r[4] = f2bf(b.x); r[5] = f2bf(b.y); r[6] = f2bf(b.z); r[7] = f2bf(b.w);
  return r;
}

typedef const __attribute__((address_space(1))) void* gptr1;
typedef __attribute__((address_space(3))) void* lptr3;
__device__ __forceinline__ void gl_lds16(const void* g, void* l) {
  __builtin_amdgcn_global_load_lds((gptr1)g, (lptr3)l, 16, 0, 0);
}

// ---------------- fp32 -> bf16 conversion (memory-bound) ----------------
__global__ __launch_bounds__(256)
void f32_to_bf16(const float* __restrict__ in, short* __restrict__ out, int n8) {
  int i = blockIdx.x * blockDim.x + threadIdx.x;
  if (i < n8) {
    short8 v = cvt_f32x8_bf16(in + (size_t)i * 8);
    *reinterpret_cast<short8*>(out + (size_t)i * 8) = v;
  }
}

// fused conversion: x (8192 blocks) + Wkv (1024) + Wq (512) + Wproj (512)
__global__ __launch_bounds__(256)
void conv_all(const float* __restrict__ x, const float* __restrict__ Wkv,
              const float* __restrict__ Wq, const float* __restrict__ Wproj,
              short* __restrict__ xb, short* __restrict__ wkvb,
              short* __restrict__ wqb, short* __restrict__ wprojb) {
  const float* src; short* dst; size_t off;
  int bi = blockIdx.x;
  size_t i = (size_t)bi * 256 + threadIdx.x;
  if (bi < 8192)      { src = x;     dst = xb;     off = i; }
  else if (bi < 9216) { src = Wkv;   dst = wkvb;   off = i - (size_t)8192 * 256; }
  else if (bi < 9728) { src = Wq;    dst = wqb;    off = i - (size_t)9216 * 256; }
  else                { src = Wproj; dst = wprojb; off = i - (size_t)9728 * 256; }
  short8 v = cvt_f32x8_bf16(src + off * 8);
  *reinterpret_cast<short8*>(dst + off * 8) = v;
}

// ============ 256x256 8-phase GEMM for kv (main loop unchanged) ====
// NEW: vt-half epilogue repacked through per-wave LDS -> coalesced short8
// stores along n (was 32 scattered 8B stores/lane at 8KB stride).
__global__ __launch_bounds__(512, 2)
void gemm256_kv(const short* __restrict__ A, const short* __restrict__ B,
                short* __restrict__ k_out, short* __restrict__ vt,
                int M, int N, int K)
{
  __shared__ __align__(16) short lds[2][2][2][128 * 64]; // [parity][A/B][slot][row*64]

  const int tid  = threadIdx.x;
  const int lane = tid & 63;
  const int w    = tid >> 6;
  const int wm   = w >> 2;
  const int wn   = w & 3;
  const int cl   = lane & 15;
  const int hi   = lane >> 4;
  const int srl  = lane >> 3;
  const int gch8 = (((lane & 7) ^ srl) << 3);

  const int ntile = N >> 8;
  int bid = blockIdx.x;
  { int cpx = gridDim.x >> 3; bid = (bid & 7) * cpx + (bid >> 3); }
  const int tm = bid / ntile, tn = bid % ntile;
  const int m0 = tm << 8, n0 = tn << 8;
  const int NT = K >> 6;

  auto stageA = [&](int par, int slot, int ktX) {
    #pragma unroll
    for (int j = 0; j < 2; ++j) {
      const int sr = (w << 4) + (j << 3) + srl;
      const int tr = ((sr >> 6) << 7) + (slot << 6) + (sr & 63);
      gl_lds16(A + (size_t)(m0 + tr) * K + ktX + gch8,
               (void*)&lds[par][0][slot][((w << 4) + (j << 3)) * 64]);
    }
  };
  auto stageB = [&](int par, int slot, int ktX) {
    #pragma unroll
    for (int j = 0; j < 2; ++j) {
      const int sr = (w << 4) + (j << 3) + srl;
      const int tr = ((sr >> 5) << 6) + (slot << 5) + (sr & 31);
      gl_lds16(B + (size_t)(n0 + tr) * K + ktX + gch8,
               (void*)&lds[par][1][slot][((w << 4) + (j << 3)) * 64]);
    }
  };

  const floatx4 fzero = {0.f, 0.f, 0.f, 0.f};
  floatx4 acc[8][4];
  #pragma unroll
  for (int m = 0; m < 8; ++m)
    #pragma unroll
    for (int n = 0; n < 4; ++n)
      acc[m][n] = fzero;

  short8 af[4][2], b0[2][2], b1[2][2];

  auto readA = [&](int par, int slot) {
    #pragma unroll
    for (int m = 0; m < 4; ++m)
      #pragma unroll
      for (int ks = 0; ks < 2; ++ks) {
        const int sr = (wm << 6) + (m << 4) + cl;
        const int cpos = ((((ks << 2) + hi) ^ (sr & 7)) << 3);
        af[m][ks] = *reinterpret_cast<const short8*>(&lds[par][0][slot][sr * 64 + cpos]);
      }
  };
  auto readB = [&](int par, int slot, short8 (&bf)[2][2]) {
    #pragma unroll
    for (int n = 0; n < 2; ++n)
      #pragma unroll
      for (int ks = 0; ks < 2; ++ks) {
        const int sr = (wn << 5) + (n << 4) + cl;
        const int cpos = ((((ks << 2) + hi) ^ (sr & 7)) << 3);
        bf[n][ks] = *reinterpret_cast<const short8*>(&lds[par][1][slot][sr * 64 + cpos]);
      }
  };

  #define QUAD(BF, MH, NH)                                                     \
    __builtin_amdgcn_s_setprio(1);                                             \
    _Pragma("unroll")                                                          \
    for (int ks = 0; ks < 2; ++ks)                                             \
      _Pragma("unroll")                                                        \
      for (int m = 0; m < 4; ++m)                                              \
        _Pragma("unroll")                                                      \
        for (int n = 0; n < 2; ++n)                                            \
          acc[(MH)*4 + m][(NH)*2 + n] = __builtin_amdgcn_mfma_f32_16x16x32_bf16( \
              af[m][ks], BF[n][ks], acc[(MH)*4 + m][(NH)*2 + n], 0, 0, 0);     \
    __builtin_amdgcn_s_setprio(0);

  stageA(0, 0, 0); stageB(0, 0, 0); stageB(0, 1, 0); stageA(0, 1, 0);
  stageA(1, 0, 64); stageB(1, 0, 64); stageB(1, 1, 64);
  WAIT_VM(6); BAR(); FENCE();

  for (int t = 0; t < NT; ++t) {
    const int p  = t & 1;
    const int pn = p ^ 1;
    int t1 = t + 1; if (t1 >= NT) t1 -= NT;
    int t2 = t + 2; if (t2 >= NT) t2 -= NT;
    const int kt1 = t1 << 6;
    const int kt2 = t2 << 6;

    readA(p, 0); readB(p, 0, b0);
    stageA(pn, 1, kt1);
    BAR(); WAIT_LGKM0();
    QUAD(b0, 0, 0);
    BAR(); FENCE();

    readB(p, 1, b1);
    stageA(p, 0, kt2);
    BAR(); WAIT_LGKM0();
    QUAD(b1, 0, 1);
    BAR(); FENCE();

    readA(p, 1);
    stageB(p, 0, kt2);
    BAR(); WAIT_LGKM0();
    QUAD(b0, 1, 0);
    BAR(); FENCE();

    stageB(p, 1, kt2);
    WAIT_VM(6);
    BAR(); WAIT_LGKM0();
    QUAD(b1, 1, 1);
    BAR(); FENCE();
  }

  const int rq = hi << 2;
  if (n0 < 1024) {
    // ---- k-half epilogue (unchanged) ----
    WAIT_VM(0);
    #pragma unroll
    for (int Mi = 0; Mi < 8; ++Mi) {
      #pragma unroll
      for (int Nn = 0; Nn < 4; ++Nn) {
        const int grow = m0 + wm * 128 + Mi * 16 + rq;
        const int gcol = n0 + wn * 64 + Nn * 16 + cl;
        #pragma unroll
        for (int i = 0; i < 4; ++i)
          k_out[(size_t)(grow + i) * 1024 + gcol] = f2bf(acc[Mi][Nn][i]);
      }
    }
  } else {
    // ---- vt-half epilogue: per-wave LDS repack -> coalesced short8 stores
    WAIT_VM(0); BAR(); FENCE();   // all waves' in-flight gl_lds retired before LDS reuse
    short* lt = &lds[0][0][0][0] + w * 8192;   // wave-private 16KB [64 cols][128 rows]
    #pragma unroll
    for (int Mi = 0; Mi < 8; ++Mi) {
      #pragma unroll
      for (int Nn = 0; Nn < 4; ++Nn) {
        const int col = Nn * 16 + cl;
        const int sw  = ((col & 7) << 1) ^ ((col & 8) >> 2);   // even swizzle key
        const int u   = (Mi * 4 + hi) ^ sw;                    // row-quad, swizzled
        short4 pk;
        pk.x = f2bf(acc[Mi][Nn][0]); pk.y = f2bf(acc[Mi][Nn][1]);
        pk.z = f2bf(acc[Mi][Nn][2]); pk.w = f2bf(acc[Mi][Nn][3]);
        *reinterpret_cast<short4*>(&lt[col * 128 + u * 4]) = pk;
      }
    }
    WAIT_LGKM0();
    const int dbase = (tn - 4) * 256 + wn * 64;   // d for col 0 (multiple of 64)
    const int hh    = dbase >> 6;
    const int grow0 = m0 + wm * 128;
    const int bb    = grow0 >> 12;
    const int nnb   = grow0 & 4095;
    const int Lr    = lane & 15;
    const int cq    = lane >> 4;
    size_t vtb = ((size_t)(bb * 16 + hh) * 64) * 4096 + nnb;
    #pragma unroll
    for (int p = 0; p < 16; ++p) {
      const int col_r = p * 4 + cq;
      const int sw    = ((col_r & 7) << 1) ^ ((col_r & 8) >> 2);
      const int u     = (Lr * 2) ^ sw;                         // even -> b128 ok
      short8 v = *reinterpret_cast<const short8*>(&lt[col_r * 128 + u * 4]);
      *reinterpret_cast<short8*>(&vt[vtb + (size_t)col_r * 4096 + Lr * 8]) = v;
    }
  }
}

// ---------------- 64x64-tile GEMM for skinny projections ------
template<int MODE>
__global__ __launch_bounds__(256, 4)
void gemm64(const short* __restrict__ A, const short* __restrict__ B,
            void* __restrict__ O0, const float* __restrict__ bias,
            int M, int N, int K, float oscale)
{
  __shared__ __align__(16) short As[64 * 64];
  __shared__ __align__(16) short Bs[64 * 64];

  const int tid  = threadIdx.x;
  const int lane = tid & 63;
  const int w    = tid >> 6;
  const int ntile = N >> 6;
  int bid = blockIdx.x;
  { int cpx = gridDim.x >> 3; bid = (bid & 7) * cpx + (bid >> 3); }
  const int tm = bid / ntile;
  const int tn = bid % ntile;
  const int m0 = tm << 6, n0 = tn << 6;
  const int wr = (w >> 1) << 5;
  const int wc = (w & 1) << 5;
  const int cl = lane & 15;
  const int hi = lane >> 4;
  const int srow = lane >> 3;
  const int scol = (lane & 7) << 3;

  const floatx4 fzero = {0.f, 0.f, 0.f, 0.f};
  floatx4 acc[2][2];
  #pragma unroll
  for (int m = 0; m < 2; ++m)
    #pragma unroll
    for (int n = 0; n < 2; ++n)
      acc[m][n] = fzero;

  for (int kt = 0; kt < K; kt += 64) {
    #pragma unroll
    for (int i = 0; i < 2; ++i) {
      const int chunk = (w << 1) + i;
      const int row   = (chunk << 3) + srow;
      gl_lds16(A + (size_t)(m0 + row) * K + kt + scol, &As[chunk * 512]);
      gl_lds16(B + (size_t)(n0 + row) * K + kt + scol, &Bs[chunk * 512]);
    }
    __syncthreads();

    #pragma unroll
    for (int ks = 0; ks < 2; ++ks) {
      short8 af[2], bfr[2];
      #pragma unroll
      for (int m = 0; m < 2; ++m)
        af[m] = *reinterpret_cast<const short8*>(
            &As[(wr + m * 16 + cl) * 64 + ks * 32 + (hi << 3)]);
      #pragma unroll
      for (int n = 0; n < 2; ++n)
        bfr[n] = *reinterpret_cast<const short8*>(
            &Bs[(wc + n * 16 + cl) * 64 + ks * 32 + (hi << 3)]);
      #pragma unroll
      for (int m = 0; m < 2; ++m)
        #pragma unroll
        for (int n = 0; n < 2; ++n)
          acc[m][n] = __builtin_amdgcn_mfma_f32_16x16x32_bf16(af[m], bfr[n], acc[m][n], 0, 0, 0);
    }
    __syncthreads();
  }

  const int rq = hi << 2;
  #pragma unroll
  for (int m = 0; m < 2; ++m) {
    #pragma unroll
    for (int n = 0; n < 2; ++n) {
      const int grow = m0 + wr + m * 16 + rq;
      const int gcol = n0 + wc + n * 16 + cl;
      if (MODE == 0) {
        short* o = (short*)O0;
        #pragma unroll
        for (int i = 0; i < 4; ++i)
          o[(size_t)(grow + i) * N + gcol] = f2bf(acc[m][n][i] * oscale);
      } else {
        float* o = (float*)O0;
        const float bv = bias[gcol];
        #pragma unroll
        for (int i = 0; i < 4; ++i)
          o[(size_t)(grow + i) * N + gcol] = acc[m][n][i] + bv;
      }
    }
  }
}

// ---------------- flash attention: 4-ring + counted vmcnt(4) (~81 µs) ----
__global__ __launch_bounds__(256, 2)
void attn_fwd(const short* __restrict__ q_ws, const short* __restrict__ k_ws,
              const short* __restrict__ vt_ws, short* __restrict__ ao_ws)
{
  __shared__ __align__(16) short Ks[4][64 * 64];
  __shared__ __align__(16) short Vts[4][64 * 64];
  __shared__ __align__(16) short Pl[4][32 * 64];

  const int tid  = threadIdx.x;
  const int lane = tid & 63;
  const int w    = tid >> 6;
  const int i    = blockIdx.x;
  const int bh   = (i & 7) * 8 + (i >> 6);   // same bh -> same i%8 -> same XCD
  const int qt   = (i >> 3) & 7;
  const int b  = bh >> 4;
  const int h  = bh & 15;
  const int q0 = qt * 128 + w * 32;
  const int cl = lane & 15;
  const int hi = lane >> 4;
  const int rq = hi << 2;
  const int key7 = cl & 7;

  short8 qf[2][2];
  #pragma unroll
  for (int tt = 0; tt < 2; ++tt)
    #pragma unroll
    for (int ks = 0; ks < 2; ++ks) {
      size_t idx = (size_t)(b * 1024 + q0 + tt * 16 + cl) * 1024
                 + h * 64 + ks * 32 + (hi << 3);
      qf[tt][ks] = *reinterpret_cast<const short8*>(&q_ws[idx]);
    }

  int koff[2];
  #pragma unroll
  for (int ks = 0; ks < 2; ++ks)
    koff[ks] = cl * 64 + ((((ks << 2) + hi) ^ key7) << 3);
  const int pwc   = hi >> 1;
  const int pwoff = (hi & 1) << 2;
  int pwch[4];
  #pragma unroll
  for (int n = 0; n < 4; ++n)
    pwch[n] = ((((n << 1) + pwc) ^ key7) << 3) + pwoff + cl * 64;

  const floatx4 fzero = {0.f, 0.f, 0.f, 0.f};
  floatx4 o[2][4];
  floatx4 ol[2];
  floatx4 s[4][2];
  short8 vones;
  #pragma unroll
  for (int j = 0; j < 8; ++j) vones[j] = (short)0x3F80;  // bf16 1.0
  #pragma unroll
  for (int tt = 0; tt < 2; ++tt) {
    ol[tt] = fzero;
    #pragma unroll
    for (int nd = 0; nd < 4; ++nd) o[tt][nd] = fzero;
  }

  const int c0    = w << 1;
  const int srow8 = lane >> 3;
  const int gch8  = (((lane & 7) ^ srow8) << 3);
  const short* kbase = k_ws + (size_t)(b * 4096 + (c0 << 3) + srow8) * 1024 + h * 64 + gch8;
  const short* vbase = vt_ws + ((size_t)bh * 64 + (c0 << 3) + srow8) * 4096 + gch8;

  auto stage = [&](int buf, int kv0) {
    gl_lds16(kbase + (size_t)kv0 * 1024,          (void*)&Ks[buf][c0 * 512]);
    gl_lds16(kbase + (size_t)kv0 * 1024 + 8192,   (void*)&Ks[buf][(c0 + 1) * 512]);
    gl_lds16(vbase + kv0,                          (void*)&Vts[buf][c0 * 512]);
    gl_lds16(vbase + kv0 + 8 * 4096,               (void*)&Vts[buf][(c0 + 1) * 512]);
  };

  auto qk = [&](const short* kb) {            // writes s fresh (zero C on ks=0)
    short8 kf[2][4];
    #pragma unroll
    for (int ks = 0; ks < 2; ++ks)
      #pragma unroll
      for (int n = 0; n < 4; ++n)
        kf[ks][n] = *reinterpret_cast<const short8*>(kb + koff[ks] + n * 1024);
    #pragma unroll
    for (int n = 0; n < 4; ++n)
      #pragma unroll
      for (int tt = 0; tt < 2; ++tt)
        s[n][tt] = __builtin_amdgcn_mfma_f32_16x16x32_bf16(
            kf[1][n], qf[tt][1],
            __builtin_amdgcn_mfma_f32_16x16x32_bf16(kf[0][n], qf[tt][0], fzero, 0, 0, 0),
            0, 0, 0);
  };
  auto pv = [&](const short* plb, const short* vb) {
    #pragma unroll
    for (int ks = 0; ks < 2; ++ks) {
      short8 pa[2], vf[4];
      #pragma unroll
      for (int tt = 0; tt < 2; ++tt)
        pa[tt] = *reinterpret_cast<const short8*>(plb + koff[ks] + tt * 1024);
      #pragma unroll
      for (int nd = 0; nd < 4; ++nd)
        vf[nd] = *reinterpret_cast<const short8*>(vb + koff[ks] + nd * 1024);
      #pragma unroll
      for (int tt = 0; tt < 2; ++tt) {
        ol[tt] = __builtin_amdgcn_mfma_f32_16x16x32_bf16(pa[tt], vones, ol[tt], 0, 0, 0);
        #pragma unroll
        for (int nd = 0; nd < 4; ++nd)
          o[tt][nd] = __builtin_amdgcn_mfma_f32_16x16x32_bf16(pa[tt], vf[nd], o[tt][nd], 0, 0, 0);
      }
    }
  };
  auto smax = [&](short* plw) {
    #pragma unroll
    for (int tt = 0; tt < 2; ++tt)
      #pragma unroll
      for (int n = 0; n < 4; ++n) {
        short4 pk;
        #pragma unroll
        for (int ii = 0; ii < 4; ++ii)
          pk[ii] = f2bf(EXP2(s[n][tt][ii]));
        *reinterpret_cast<short4*>(plw + tt * 1024 + pwch[n]) = pk;
      }
  };

  // ---- prologue: stage 0,1,2 -> QK(0) -> softmax(0)
  stage(0, 0);
  stage(1, 64);
  stage(2, 128);
  WAIT_VM(8); BAR(); FENCE();     // qf + tile 0 landed; tiles 1,2 in flight
  qk(&Ks[0][0]);
  smax(&Pl[w][0]);

  // ---- main loop: one barrier/iter; counted vmcnt keeps 1 extra tile in flight
  for (int t = 0; t < 63; ++t) {
    WAIT_VM(4); BAR(); FENCE();          // tile t+1 landed; tile t+2 in flight
    __builtin_amdgcn_s_setprio(1);
    qk(&Ks[(t + 1) & 3][0]);             // K[t+1] (fresh s)
    pv(&Pl[w][0], &Vts[t & 3][0]);       // P[t] x V[t] + ones row-sum
    __builtin_amdgcn_s_setprio(0);
    stage((t + 3) & 3, ((t + 3) & 63) << 6);  // slot last read at iter t-1
    smax(&Pl[w][0]);                     // P[t+1]
  }
  // ---- epilogue: PV(63); V[63] (slot 3) landed at iter 62's wait
  __builtin_amdgcn_s_setprio(1);
  pv(&Pl[w][0], &Vts[3][0]);
  __builtin_amdgcn_s_setprio(0);
  WAIT_VM(0);

  // finalize: ol[m][ii] = l[q = m*16 + rq + ii] exactly -> no shuffles
  #pragma unroll
  for (int m = 0; m < 2; ++m) {
    float inv[4];
    #pragma unroll
    for (int ii = 0; ii < 4; ++ii)
      inv[ii] = 1.f / ol[m][ii];
    #pragma unroll
    for (int nd = 0; nd < 4; ++nd)
      #pragma unroll
      for (int ii = 0; ii < 4; ++ii) {
        size_t idx = (size_t)(b * 1024 + q0 + m * 16 + rq + ii) * 1024
                   + h * 64 + nd * 16 + cl;
        ao_ws[idx] = f2bf(o[m][nd][ii] * inv[ii]);
      }
  }
}

extern "C" void kernel_launch(void* const* d_in, const int* in_sizes, int n_in,
                              void* d_out, int out_size, void* d_ws, size_t ws_size,
                              hipStream_t stream)
{
  const float* x     = (const float*)d_in[0];
  const float* query = (const float*)d_in[1];
  const float* Wq    = (const float*)d_in[2];
  const float* Wkv   = (const float*)d_in[3];
  const float* Wproj = (const float*)d_in[4];
  const float* bproj = (const float*)d_in[5];
  float* out = (float*)d_out;

  const float QSCALE = 0.18033688011112042f;  // (1/sqrt(64)) * log2(e)

  char* ws = (char*)d_ws;
  short* k_ws   = (short*)(ws);
  short* vt_ws  = (short*)(ws + (32ull << 20));
  short* xb     = (short*)(ws + (64ull << 20));   // dead after kv gemm
  short* qb     = (short*)(ws + (64ull << 20));   // written after kv gemm
  short* q_ws   = (short*)(ws + (72ull << 20));
  short* ao_ws  = (short*)(ws + (80ull << 20));
  short* wkvb   = (short*)(ws + (96ull << 20));
  short* wqb    = (short*)(ws + (100ull << 20));
  short* wprojb = (short*)(ws + (102ull << 20));

  // fused: x + all 3 weights in one dispatch
  conv_all<<<dim3(10240), 256, 0, stream>>>(x, Wkv, Wq, Wproj,
                                            xb, wkvb, wqb, wprojb);
  gemm256_kv<<<dim3(512), 512, 0, stream>>>(xb, wkvb, k_ws, vt_ws,
                                            16384, 2048, 1024);
  f32_to_bf16<<<dim3(2048), 256, 0, stream>>>(query, qb, (4096 * 1024) / 8);
  gemm64<0><<<dim3(1024), 256, 0, stream>>>(qb, wqb, q_ws, nullptr,
                                            4096, 1024, 1024, QSCALE);
  attn_fwd<<<dim3(512), 256, 0, stream>>>(q_ws, k_ws, vt_ws, ao_ws);
  gemm64<2><<<dim3(1024), 256, 0, stream>>>(ao_ws, wprojb, out, bproj,
                                            4096, 1024, 1024, 1.0f);
}

// Round 22
// 201.189 us; speedup vs baseline: 1.3998x; 1.0181x over previous
//
#include <hip/hip_runtime.h>
#include <hip/hip_bf16.h>

typedef __attribute__((ext_vector_type(8))) short short8;
typedef __attribute__((ext_vector_type(4))) float floatx4;

#if __has_builtin(__builtin_amdgcn_exp2f)
#define EXP2(x) __builtin_amdgcn_exp2f(x)
#else
#define EXP2(x) exp2f(x)
#endif

#define BAR() __builtin_amdgcn_s_barrier()
#define FENCE() asm volatile("" ::: "memory")
#define WAIT_LGKM0() asm volatile("s_waitcnt lgkmcnt(0)" ::: "memory")
#define WAIT_VM(n) asm volatile("s_waitcnt vmcnt(" #n ")" ::: "memory")

__device__ __forceinline__ short f2bf(float f) {
  __hip_bfloat16 h = __float2bfloat16(f);
  return *reinterpret_cast<const short*>(&h);
}

__device__ __forceinline__ short8 cvt_f32x8_bf16(const float* __restrict__ p) {
  float4 a = *reinterpret_cast<const float4*>(p);
  float4 b = *reinterpret_cast<const float4*>(p + 4);
  short8 r;
  r[0] = f2bf(a.x); r[1] = f2bf(a.y); r[2] = f2bf(a.z); r[3] = f2bf(a.w);
  r[4] = f2bf(b.x); r[5] = f2bf(b.y); r[6] = f2bf(b.z); r[7] = f2bf(b.w);
  return r;
}

typedef const __attribute__((address_space(1))) void* gptr1;
typedef __attribute__((address_space(3))) void* lptr3;
__device__ __forceinline__ void gl_lds16(const void* g, void* l) {
  __builtin_amdgcn_global_load_lds((gptr1)g, (lptr3)l, 16, 0, 0);
}

// ---------------- fp32 -> bf16 conversion (memory-bound) ----------------
__global__ __launch_bounds__(256)
void f32_to_bf16(const float* __restrict__ in, short* __restrict__ out, int n8) {
  int i = blockIdx.x * blockDim.x + threadIdx.x;
  if (i < n8) {
    short8 v = cvt_f32x8_bf16(in + (size_t)i * 8);
    *reinterpret_cast<short8*>(out + (size_t)i * 8) = v;
  }
}

// fused conversion: x (8192) + Wkv (1024) + Wq (512) + Wproj (512) [+ query 2048]
__global__ __launch_bounds__(256)
void conv_all(const float* __restrict__ x, const float* __restrict__ Wkv,
              const float* __restrict__ Wq, const float* __restrict__ Wproj,
              const float* __restrict__ query,
              short* __restrict__ xb, short* __restrict__ wkvb,
              short* __restrict__ wqb, short* __restrict__ wprojb,
              short* __restrict__ qb) {
  const float* src; short* dst; size_t off;
  int bi = blockIdx.x;
  size_t i = (size_t)bi * 256 + threadIdx.x;
  if (bi < 8192)       { src = x;     dst = xb;     off = i; }
  else if (bi < 9216)  { src = Wkv;   dst = wkvb;   off = i - (size_t)8192 * 256; }
  else if (bi < 9728)  { src = Wq;    dst = wqb;    off = i - (size_t)9216 * 256; }
  else if (bi < 10240) { src = Wproj; dst = wprojb; off = i - (size_t)9728 * 256; }
  else                 { src = query; dst = qb;     off = i - (size_t)10240 * 256; }
  short8 v = cvt_f32x8_bf16(src + off * 8);
  *reinterpret_cast<short8*>(dst + off * 8) = v;
}

// ============ 256x256 8-phase GEMM for kv (round-21: LDS-repacked vt) ====
__global__ __launch_bounds__(512, 2)
void gemm256_kv(const short* __restrict__ A, const short* __restrict__ B,
                short* __restrict__ k_out, short* __restrict__ vt,
                int M, int N, int K)
{
  __shared__ __align__(16) short lds[2][2][2][128 * 64]; // [parity][A/B][slot][row*64]

  const int tid  = threadIdx.x;
  const int lane = tid & 63;
  const int w    = tid >> 6;
  const int wm   = w >> 2;
  const int wn   = w & 3;
  const int cl   = lane & 15;
  const int hi   = lane >> 4;
  const int srl  = lane >> 3;
  const int gch8 = (((lane & 7) ^ srl) << 3);

  const int ntile = N >> 8;
  int bid = blockIdx.x;
  { int cpx = gridDim.x >> 3; bid = (bid & 7) * cpx + (bid >> 3); }
  const int tm = bid / ntile, tn = bid % ntile;
  const int m0 = tm << 8, n0 = tn << 8;
  const int NT = K >> 6;

  auto stageA = [&](int par, int slot, int ktX) {
    #pragma unroll
    for (int j = 0; j < 2; ++j) {
      const int sr = (w << 4) + (j << 3) + srl;
      const int tr = ((sr >> 6) << 7) + (slot << 6) + (sr & 63);
      gl_lds16(A + (size_t)(m0 + tr) * K + ktX + gch8,
               (void*)&lds[par][0][slot][((w << 4) + (j << 3)) * 64]);
    }
  };
  auto stageB = [&](int par, int slot, int ktX) {
    #pragma unroll
    for (int j = 0; j < 2; ++j) {
      const int sr = (w << 4) + (j << 3) + srl;
      const int tr = ((sr >> 5) << 6) + (slot << 5) + (sr & 31);
      gl_lds16(B + (size_t)(n0 + tr) * K + ktX + gch8,
               (void*)&lds[par][1][slot][((w << 4) + (j << 3)) * 64]);
    }
  };

  const floatx4 fzero = {0.f, 0.f, 0.f, 0.f};
  floatx4 acc[8][4];
  #pragma unroll
  for (int m = 0; m < 8; ++m)
    #pragma unroll
    for (int n = 0; n < 4; ++n)
      acc[m][n] = fzero;

  short8 af[4][2], b0[2][2], b1[2][2];

  auto readA = [&](int par, int slot) {
    #pragma unroll
    for (int m = 0; m < 4; ++m)
      #pragma unroll
      for (int ks = 0; ks < 2; ++ks) {
        const int sr = (wm << 6) + (m << 4) + cl;
        const int cpos = ((((ks << 2) + hi) ^ (sr & 7)) << 3);
        af[m][ks] = *reinterpret_cast<const short8*>(&lds[par][0][slot][sr * 64 + cpos]);
      }
  };
  auto readB = [&](int par, int slot, short8 (&bf)[2][2]) {
    #pragma unroll
    for (int n = 0; n < 2; ++n)
      #pragma unroll
      for (int ks = 0; ks < 2; ++ks) {
        const int sr = (wn << 5) + (n << 4) + cl;
        const int cpos = ((((ks << 2) + hi) ^ (sr & 7)) << 3);
        bf[n][ks] = *reinterpret_cast<const short8*>(&lds[par][1][slot][sr * 64 + cpos]);
      }
  };

  #define QUAD(BF, MH, NH)                                                     \
    __builtin_amdgcn_s_setprio(1);                                             \
    _Pragma("unroll")                                                          \
    for (int ks = 0; ks < 2; ++ks)                                             \
      _Pragma("unroll")                                                        \
      for (int m = 0; m < 4; ++m)                                              \
        _Pragma("unroll")                                                      \
        for (int n = 0; n < 2; ++n)                                            \
          acc[(MH)*4 + m][(NH)*2 + n] = __builtin_amdgcn_mfma_f32_16x16x32_bf16( \
              af[m][ks], BF[n][ks], acc[(MH)*4 + m][(NH)*2 + n], 0, 0, 0);     \
    __builtin_amdgcn_s_setprio(0);

  stageA(0, 0, 0); stageB(0, 0, 0); stageB(0, 1, 0); stageA(0, 1, 0);
  stageA(1, 0, 64); stageB(1, 0, 64); stageB(1, 1, 64);
  WAIT_VM(6); BAR(); FENCE();

  for (int t = 0; t < NT; ++t) {
    const int p  = t & 1;
    const int pn = p ^ 1;
    int t1 = t + 1; if (t1 >= NT) t1 -= NT;
    int t2 = t + 2; if (t2 >= NT) t2 -= NT;
    const int kt1 = t1 << 6;
    const int kt2 = t2 << 6;

    readA(p, 0); readB(p, 0, b0);
    stageA(pn, 1, kt1);
    BAR(); WAIT_LGKM0();
    QUAD(b0, 0, 0);
    BAR(); FENCE();

    readB(p, 1, b1);
    stageA(p, 0, kt2);
    BAR(); WAIT_LGKM0();
    QUAD(b1, 0, 1);
    BAR(); FENCE();

    readA(p, 1);
    stageB(p, 0, kt2);
    BAR(); WAIT_LGKM0();
    QUAD(b0, 1, 0);
    BAR(); FENCE();

    stageB(p, 1, kt2);
    WAIT_VM(6);
    BAR(); WAIT_LGKM0();
    QUAD(b1, 1, 1);
    BAR(); FENCE();
  }

  const int rq = hi << 2;
  if (n0 < 1024) {
    // ---- k-half epilogue ----
    WAIT_VM(0);
    #pragma unroll
    for (int Mi = 0; Mi < 8; ++Mi) {
      #pragma unroll
      for (int Nn = 0; Nn < 4; ++Nn) {
        const int grow = m0 + wm * 128 + Mi * 16 + rq;
        const int gcol = n0 + wn * 64 + Nn * 16 + cl;
        #pragma unroll
        for (int i = 0; i < 4; ++i)
          k_out[(size_t)(grow + i) * 1024 + gcol] = f2bf(acc[Mi][Nn][i]);
      }
    }
  } else {
    // ---- vt-half epilogue: per-wave LDS repack -> coalesced short8 stores
    WAIT_VM(0); BAR(); FENCE();
    short* lt = &lds[0][0][0][0] + w * 8192;   // wave-private 16KB [64 cols][128 rows]
    #pragma unroll
    for (int Mi = 0; Mi < 8; ++Mi) {
      #pragma unroll
      for (int Nn = 0; Nn < 4; ++Nn) {
        const int col = Nn * 16 + cl;
        const int sw  = ((col & 7) << 1) ^ ((col & 8) >> 2);
        const int u   = (Mi * 4 + hi) ^ sw;
        short4 pk;
        pk.x = f2bf(acc[Mi][Nn][0]); pk.y = f2bf(acc[Mi][Nn][1]);
        pk.z = f2bf(acc[Mi][Nn][2]); pk.w = f2bf(acc[Mi][Nn][3]);
        *reinterpret_cast<short4*>(&lt[col * 128 + u * 4]) = pk;
      }
    }
    WAIT_LGKM0();
    const int dbase = (tn - 4) * 256 + wn * 64;
    const int hh    = dbase >> 6;
    const int grow0 = m0 + wm * 128;
    const int bb    = grow0 >> 12;
    const int nnb   = grow0 & 4095;
    const int Lr    = lane & 15;
    const int cq    = lane >> 4;
    size_t vtb = ((size_t)(bb * 16 + hh) * 64) * 4096 + nnb;
    #pragma unroll
    for (int p = 0; p < 16; ++p) {
      const int col_r = p * 4 + cq;
      const int sw    = ((col_r & 7) << 1) ^ ((col_r & 8) >> 2);
      const int u     = (Lr * 2) ^ sw;
      short8 v = *reinterpret_cast<const short8*>(&lt[col_r * 128 + u * 4]);
      *reinterpret_cast<short8*>(&vt[vtb + (size_t)col_r * 4096 + Lr * 8]) = v;
    }
  }
}

// ---------------- 64x64-tile GEMM for skinny projections ------
template<int MODE>
__global__ __launch_bounds__(256, 4)
void gemm64(const short* __restrict__ A, const short* __restrict__ B,
            void* __restrict__ O0, const float* __restrict__ bias,
            int M, int N, int K, float oscale)
{
  __shared__ __align__(16) short As[64 * 64];
  __shared__ __align__(16) short Bs[64 * 64];

  const int tid  = threadIdx.x;
  const int lane = tid & 63;
  const int w    = tid >> 6;
  const int ntile = N >> 6;
  int bid = blockIdx.x;
  { int cpx = gridDim.x >> 3; bid = (bid & 7) * cpx + (bid >> 3); }
  const int tm = bid / ntile;
  const int tn = bid % ntile;
  const int m0 = tm << 6, n0 = tn << 6;
  const int wr = (w >> 1) << 5;
  const int wc = (w & 1) << 5;
  const int cl = lane & 15;
  const int hi = lane >> 4;
  const int srow = lane >> 3;
  const int scol = (lane & 7) << 3;

  const floatx4 fzero = {0.f, 0.f, 0.f, 0.f};
  floatx4 acc[2][2];
  #pragma unroll
  for (int m = 0; m < 2; ++m)
    #pragma unroll
    for (int n = 0; n < 2; ++n)
      acc[m][n] = fzero;

  for (int kt = 0; kt < K; kt += 64) {
    #pragma unroll
    for (int i = 0; i < 2; ++i) {
      const int chunk = (w << 1) + i;
      const int row   = (chunk << 3) + srow;
      gl_lds16(A + (size_t)(m0 + row) * K + kt + scol, &As[chunk * 512]);
      gl_lds16(B + (size_t)(n0 + row) * K + kt + scol, &Bs[chunk * 512]);
    }
    __syncthreads();

    #pragma unroll
    for (int ks = 0; ks < 2; ++ks) {
      short8 af[2], bfr[2];
      #pragma unroll
      for (int m = 0; m < 2; ++m)
        af[m] = *reinterpret_cast<const short8*>(
            &As[(wr + m * 16 + cl) * 64 + ks * 32 + (hi << 3)]);
      #pragma unroll
      for (int n = 0; n < 2; ++n)
        bfr[n] = *reinterpret_cast<const short8*>(
            &Bs[(wc + n * 16 + cl) * 64 + ks * 32 + (hi << 3)]);
      #pragma unroll
      for (int m = 0; m < 2; ++m)
        #pragma unroll
        for (int n = 0; n < 2; ++n)
          acc[m][n] = __builtin_amdgcn_mfma_f32_16x16x32_bf16(af[m], bfr[n], acc[m][n], 0, 0, 0);
    }
    __syncthreads();
  }

  const int rq = hi << 2;
  #pragma unroll
  for (int m = 0; m < 2; ++m) {
    #pragma unroll
    for (int n = 0; n < 2; ++n) {
      const int grow = m0 + wr + m * 16 + rq;
      const int gcol = n0 + wc + n * 16 + cl;
      if (MODE == 0) {
        short* o = (short*)O0;
        #pragma unroll
        for (int i = 0; i < 4; ++i)
          o[(size_t)(grow + i) * N + gcol] = f2bf(acc[m][n][i] * oscale);
      } else {
        float* o = (float*)O0;
        const float bv = bias[gcol];
        #pragma unroll
        for (int i = 0; i < 4; ++i)
          o[(size_t)(grow + i) * N + gcol] = acc[m][n][i] + bv;
      }
    }
  }
}

// ---------------- flash attention: 4-ring + counted vmcnt(4) (~81 µs) ----
__global__ __launch_bounds__(256, 2)
void attn_fwd(const short* __restrict__ q_ws, const short* __restrict__ k_ws,
              const short* __restrict__ vt_ws, short* __restrict__ ao_ws)
{
  __shared__ __align__(16) short Ks[4][64 * 64];
  __shared__ __align__(16) short Vts[4][64 * 64];
  __shared__ __align__(16) short Pl[4][32 * 64];

  const int tid  = threadIdx.x;
  const int lane = tid & 63;
  const int w    = tid >> 6;
  const int i    = blockIdx.x;
  const int bh   = (i & 7) * 8 + (i >> 6);   // same bh -> same i%8 -> same XCD
  const int qt   = (i >> 3) & 7;
  const int b  = bh >> 4;
  const int h  = bh & 15;
  const int q0 = qt * 128 + w * 32;
  const int cl = lane & 15;
  const int hi = lane >> 4;
  const int rq = hi << 2;
  const int key7 = cl & 7;

  short8 qf[2][2];
  #pragma unroll
  for (int tt = 0; tt < 2; ++tt)
    #pragma unroll
    for (int ks = 0; ks < 2; ++ks) {
      size_t idx = (size_t)(b * 1024 + q0 + tt * 16 + cl) * 1024
                 + h * 64 + ks * 32 + (hi << 3);
      qf[tt][ks] = *reinterpret_cast<const short8*>(&q_ws[idx]);
    }

  int koff[2];
  #pragma unroll
  for (int ks = 0; ks < 2; ++ks)
    koff[ks] = cl * 64 + ((((ks << 2) + hi) ^ key7) << 3);
  const int pwc   = hi >> 1;
  const int pwoff = (hi & 1) << 2;
  int pwch[4];
  #pragma unroll
  for (int n = 0; n < 4; ++n)
    pwch[n] = ((((n << 1) + pwc) ^ key7) << 3) + pwoff + cl * 64;

  const floatx4 fzero = {0.f, 0.f, 0.f, 0.f};
  floatx4 o[2][4];
  floatx4 ol[2];
  floatx4 s[4][2];
  short8 vones;
  #pragma unroll
  for (int j = 0; j < 8; ++j) vones[j] = (short)0x3F80;  // bf16 1.0
  #pragma unroll
  for (int tt = 0; tt < 2; ++tt) {
    ol[tt] = fzero;
    #pragma unroll
    for (int nd = 0; nd < 4; ++nd) o[tt][nd] = fzero;
  }

  const int c0    = w << 1;
  const int srow8 = lane >> 3;
  const int gch8  = (((lane & 7) ^ srow8) << 3);
  const short* kbase = k_ws + (size_t)(b * 4096 + (c0 << 3) + srow8) * 1024 + h * 64 + gch8;
  const short* vbase = vt_ws + ((size_t)bh * 64 + (c0 << 3) + srow8) * 4096 + gch8;

  auto stage = [&](int buf, int kv0) {
    gl_lds16(kbase + (size_t)kv0 * 1024,          (void*)&Ks[buf][c0 * 512]);
    gl_lds16(kbase + (size_t)kv0 * 1024 + 8192,   (void*)&Ks[buf][(c0 + 1) * 512]);
    gl_lds16(vbase + kv0,                          (void*)&Vts[buf][c0 * 512]);
    gl_lds16(vbase + kv0 + 8 * 4096,               (void*)&Vts[buf][(c0 + 1) * 512]);
  };

  auto qk = [&](const short* kb) {            // writes s fresh (zero C on ks=0)
    short8 kf[2][4];
    #pragma unroll
    for (int ks = 0; ks < 2; ++ks)
      #pragma unroll
      for (int n = 0; n < 4; ++n)
        kf[ks][n] = *reinterpret_cast<const short8*>(kb + koff[ks] + n * 1024);
    #pragma unroll
    for (int n = 0; n < 4; ++n)
      #pragma unroll
      for (int tt = 0; tt < 2; ++tt)
        s[n][tt] = __builtin_amdgcn_mfma_f32_16x16x32_bf16(
            kf[1][n], qf[tt][1],
            __builtin_amdgcn_mfma_f32_16x16x32_bf16(kf[0][n], qf[tt][0], fzero, 0, 0, 0),
            0, 0, 0);
  };
  auto pv = [&](const short* plb, const short* vb) {
    #pragma unroll
    for (int ks = 0; ks < 2; ++ks) {
      short8 pa[2], vf[4];
      #pragma unroll
      for (int tt = 0; tt < 2; ++tt)
        pa[tt] = *reinterpret_cast<const short8*>(plb + koff[ks] + tt * 1024);
      #pragma unroll
      for (int nd = 0; nd < 4; ++nd)
        vf[nd] = *reinterpret_cast<const short8*>(vb + koff[ks] + nd * 1024);
      #pragma unroll
      for (int tt = 0; tt < 2; ++tt) {
        ol[tt] = __builtin_amdgcn_mfma_f32_16x16x32_bf16(pa[tt], vones, ol[tt], 0, 0, 0);
        #pragma unroll
        for (int nd = 0; nd < 4; ++nd)
          o[tt][nd] = __builtin_amdgcn_mfma_f32_16x16x32_bf16(pa[tt], vf[nd], o[tt][nd], 0, 0, 0);
      }
    }
  };
  auto smax = [&](short* plw) {
    #pragma unroll
    for (int tt = 0; tt < 2; ++tt)
      #pragma unroll
      for (int n = 0; n < 4; ++n) {
        short4 pk;
        #pragma unroll
        for (int ii = 0; ii < 4; ++ii)
          pk[ii] = f2bf(EXP2(s[n][tt][ii]));
        *reinterpret_cast<short4*>(plw + tt * 1024 + pwch[n]) = pk;
      }
  };

  // ---- prologue: stage 0,1,2 -> QK(0) -> softmax(0)
  stage(0, 0);
  stage(1, 64);
  stage(2, 128);
  WAIT_VM(8); BAR(); FENCE();     // qf + tile 0 landed; tiles 1,2 in flight
  qk(&Ks[0][0]);
  smax(&Pl[w][0]);

  // ---- main loop: one barrier/iter; counted vmcnt keeps 1 extra tile in flight
  for (int t = 0; t < 63; ++t) {
    WAIT_VM(4); BAR(); FENCE();          // tile t+1 landed; tile t+2 in flight
    __builtin_amdgcn_s_setprio(1);
    qk(&Ks[(t + 1) & 3][0]);             // K[t+1] (fresh s)
    pv(&Pl[w][0], &Vts[t & 3][0]);       // P[t] x V[t] + ones row-sum
    __builtin_amdgcn_s_setprio(0);
    stage((t + 3) & 3, ((t + 3) & 63) << 6);  // slot last read at iter t-1
    smax(&Pl[w][0]);                     // P[t+1]
  }
  // ---- epilogue: PV(63); V[63] (slot 3) landed at iter 62's wait
  __builtin_amdgcn_s_setprio(1);
  pv(&Pl[w][0], &Vts[3][0]);
  __builtin_amdgcn_s_setprio(0);
  WAIT_VM(0);

  // finalize: ol[m][ii] = l[q = m*16 + rq + ii] exactly -> no shuffles
  #pragma unroll
  for (int m = 0; m < 2; ++m) {
    float inv[4];
    #pragma unroll
    for (int ii = 0; ii < 4; ++ii)
      inv[ii] = 1.f / ol[m][ii];
    #pragma unroll
    for (int nd = 0; nd < 4; ++nd)
      #pragma unroll
      for (int ii = 0; ii < 4; ++ii) {
        size_t idx = (size_t)(b * 1024 + q0 + m * 16 + rq + ii) * 1024
                   + h * 64 + nd * 16 + cl;
        ao_ws[idx] = f2bf(o[m][nd][ii] * inv[ii]);
      }
  }
}

extern "C" void kernel_launch(void* const* d_in, const int* in_sizes, int n_in,
                              void* d_out, int out_size, void* d_ws, size_t ws_size,
                              hipStream_t stream)
{
  const float* x     = (const float*)d_in[0];
  const float* query = (const float*)d_in[1];
  const float* Wq    = (const float*)d_in[2];
  const float* Wkv   = (const float*)d_in[3];
  const float* Wproj = (const float*)d_in[4];
  const float* bproj = (const float*)d_in[5];
  float* out = (float*)d_out;

  const float QSCALE = 0.18033688011112042f;  // (1/sqrt(64)) * log2(e)

  char* ws = (char*)d_ws;
  short* k_ws   = (short*)(ws);
  short* vt_ws  = (short*)(ws + (32ull << 20));
  short* xb     = (short*)(ws + (64ull << 20));   // [64,96M), dead after kv gemm
  short* qb_a   = (short*)(ws + (64ull << 20));   // aliased qb (post-kv path)
  short* q_ws   = (short*)(ws + (72ull << 20));
  short* ao_ws  = (short*)(ws + (80ull << 20));
  short* wkvb   = (short*)(ws + (96ull << 20));
  short* wqb    = (short*)(ws + (100ull << 20));
  short* wprojb = (short*)(ws + (102ull << 20));
  short* qb_x   = (short*)(ws + (104ull << 20));  // non-aliased qb (fused path)

  const bool fused_q = ws_size >= (113ull << 20);

  if (fused_q) {
    // one conversion dispatch for everything (qb outside xb's range)
    conv_all<<<dim3(12288), 256, 0, stream>>>(x, Wkv, Wq, Wproj, query,
                                              xb, wkvb, wqb, wprojb, qb_x);
    gemm256_kv<<<dim3(512), 512, 0, stream>>>(xb, wkvb, k_ws, vt_ws,
                                              16384, 2048, 1024);
    gemm64<0><<<dim3(1024), 256, 0, stream>>>(qb_x, wqb, q_ws, nullptr,
                                              4096, 1024, 1024, QSCALE);
  } else {
    conv_all<<<dim3(10240), 256, 0, stream>>>(x, Wkv, Wq, Wproj, query,
                                              xb, wkvb, wqb, wprojb, qb_a);
    gemm256_kv<<<dim3(512), 512, 0, stream>>>(xb, wkvb, k_ws, vt_ws,
                                              16384, 2048, 1024);
    f32_to_bf16<<<dim3(2048), 256, 0, stream>>>(query, qb_a, (4096 * 1024) / 8);
    gemm64<0><<<dim3(1024), 256, 0, stream>>>(qb_a, wqb, q_ws, nullptr,
                                              4096, 1024, 1024, QSCALE);
  }
  attn_fwd<<<dim3(512), 256, 0, stream>>>(q_ws, k_ws, vt_ws, ao_ws);
  gemm64<2><<<dim3(1024), 256, 0, stream>>>(ao_ws, wprojb, out, bproj,
                                            4096, 1024, 1024, 1.0f);
}